// Round 7
// baseline (481.261 us; speedup 1.0000x reference)
//
#include <hip/hip_runtime.h>
#include <hip/hip_bf16.h>
#include <math.h>

#define N_NODES 50000
#define N_EDGES 800000
#define CDIM 64
#define MCDIM 128
#define GSUM_REP 32   // gsum replication factor (atomic decontention)

// bf16 LDS strides (elements). Row stride in dwords must be == 4 (mod 8) so
// the 16-row A-fragment ds_read_b128 pattern lands 2 lanes/bank (free, m136).
#define XS1 168       // folded edge_input, K = 132 padded -> 160 (84 dw % 8 == 4)
#define HS  136       // hidden layers, K=128                (68 dw % 8 == 4)
#define UST 264       // update_input, K=256                (132 dw % 8 == 4)

typedef __attribute__((ext_vector_type(8))) short short8;
typedef __attribute__((ext_vector_type(4))) float floatx4;
typedef __attribute__((ext_vector_type(2))) float f32x2;

// A&S 7.1.27 erf (abs err 5e-4) gelu, scalar form (used in small kernels).
__device__ __forceinline__ float gelu_fast(float x) {
    float z = fabsf(x) * 0.70710678f;
    float w = fmaf(z, fmaf(z, fmaf(z, fmaf(z, 0.078108f, 0.000972f),
                                   0.230389f), 0.278393f), 1.0f);
    float w2 = w * w;
    float r = __builtin_amdgcn_rcpf(w2 * w2);
    float m = 0.5f * fabsf(x);
    return fmaf(-m, r, fmaf(0.5f, x, m));
}

// Packed-pair gelu: identical per-element math; float2 vector arithmetic lets
// LLVM emit dual-issue v_pk_{mul,add,fma}_f32. rcp stays scalar.
__device__ __forceinline__ f32x2 gelu_pk(f32x2 x) {
    f32x2 ax = __builtin_elementwise_abs(x);
    f32x2 z = ax * 0.70710678f;
    f32x2 w = z * (z * (z * (z * 0.078108f + 0.000972f) + 0.230389f)
                   + 0.278393f) + 1.0f;
    f32x2 w2 = w * w;
    f32x2 w4 = w2 * w2;
    f32x2 r;
    r.x = __builtin_amdgcn_rcpf(w4.x);
    r.y = __builtin_amdgcn_rcpf(w4.y);
    f32x2 m = 0.5f * ax;
    return 0.5f * x + m - m * r;
}

__device__ __forceinline__ unsigned short f2bf(float f) {  // RNE fp32->bf16
    unsigned int u = __float_as_uint(f);
    unsigned int r = u + 0x7fffu + ((u >> 16) & 1u);
    return (unsigned short)(r >> 16);
}
__device__ __forceinline__ float bf2f(unsigned int lo16) {
    return __uint_as_float(lo16 << 16);
}
// packed 2x fp32 -> bf16 pair (v_cvt_pk_bf16_f32 on gfx950)
__device__ __forceinline__ unsigned int f2bf2(float lo, float hi) {
    __hip_bfloat162 v = __float22bfloat162_rn(make_float2(lo, hi));
    union { __hip_bfloat162 b; unsigned int u; } cv;
    cv.b = v;
    return cv.u;
}
__device__ __forceinline__ ushort4 pack4(float4 v) {
    ushort4 r;
    r.x = f2bf(v.x); r.y = f2bf(v.y); r.z = f2bf(v.z); r.w = f2bf(v.w);
    return r;
}

// ---------------------------------------------------------------------------
// Weight fragment pre-swizzle. B-fragment for 16x16x32: lane l holds
// B[k = k0 + (l>>4)*8 + j][n = 16*ct + (l&15)], j=0..7 -> contiguous 16B/lane.
// ew1 is FOLDED: k<64 -> Wi+Wd ; 64..127 -> Wj-Wd ; 128..131 -> geo ; pad 160.
// FG chunk is COMPOSED: egw = ew3 @ gw1 (gate reads H2, H3 skips LDS).
// Also computes egb = eb3 @ gw1 + gb1 and zero-inits deg_int/gsum replicas.
// ---------------------------------------------------------------------------
#define F1_OFF 0               // folded ew1: 5 chunks (K=160), N=128
#define F2_OFF (5 * 4096)      // ew2: 4
#define F3_OFF (9 * 4096)      // ew3: 4
#define FG_OFF (13 * 4096)     // composed ew3@gw1: 4
#define FU1_OFF (17 * 4096)    // uw1: 8 (K=256)
#define FU2_OFF (25 * 4096)    // uw2: 4
#define FU3_OFF (29 * 4096)    // uw3: 4 chunks x 2048 (N=64)
#define FRAG_TOTAL (29 * 4096 + 4 * 2048)   // 126976 ushorts

__global__ __launch_bounds__(256) void prep_frags(
    const float* __restrict__ ew1, const float* __restrict__ ew2,
    const float* __restrict__ ew3, const float* __restrict__ gw1,
    const float* __restrict__ eb3, const float* __restrict__ gb1,
    const float* __restrict__ uw1, const float* __restrict__ uw2,
    const float* __restrict__ uw3, unsigned short* __restrict__ frags,
    int* __restrict__ deg_int, float* __restrict__ gsum,
    float* __restrict__ egb) {
    int idx = blockIdx.x * 256 + threadIdx.x;
    if (idx < N_NODES) deg_int[idx] = 0;
    if (idx < GSUM_REP * 64) gsum[idx] = 0.0f;
    if (idx < 128) {   // egb[n] = gb1[n] + eb3 . gw1[:,n]
        float s = gb1[idx];
        for (int jj = 0; jj < 128; jj++) s += eb3[jj] * gw1[jj * 128 + idx];
        egb[idx] = s;
    }
    if (idx >= FRAG_TOTAL) return;
    if (idx < F2_OFF) {  // folded ew1
        int chunk = idx >> 12;
        int rem = idx & 4095;
        int ct = rem >> 9;
        int lane = (rem >> 3) & 63;
        int j = rem & 7;
        int k = chunk * 32 + (lane >> 4) * 8 + j;
        int n = ct * 16 + (lane & 15);
        float v;
        if (k < 64)       v = ew1[k * 128 + n] + ew1[(128 + k) * 128 + n];
        else if (k < 128) v = ew1[k * 128 + n] - ew1[(64 + k) * 128 + n];
        else if (k < 132) v = ew1[(192 + k - 128) * 128 + n];
        else              v = 0.0f;
        frags[idx] = f2bf(v);
    } else if (idx >= FG_OFF && idx < FU1_OFF) {  // composed egw = ew3 @ gw1
        int chunk = idx >> 12;           // 13..16
        int rem = idx & 4095;
        int ct = rem >> 9;
        int lane = (rem >> 3) & 63;
        int j = rem & 7;
        int k = (chunk - 13) * 32 + (lane >> 4) * 8 + j;
        int n = ct * 16 + (lane & 15);
        float s = 0.0f;
        for (int jj = 0; jj < 128; jj++) s += ew3[k * 128 + jj] * gw1[jj * 128 + n];
        frags[idx] = f2bf(s);
    } else if (idx < FU3_OFF) {
        int chunk = idx >> 12;
        int rem = idx & 4095;
        int ct = rem >> 9;
        int lane = (rem >> 3) & 63;
        int j = rem & 7;
        const float* W; int kbase;
        if (chunk < 9)       { W = ew2; kbase = (chunk - 5) * 32; }
        else if (chunk < 13) { W = ew3; kbase = (chunk - 9) * 32; }
        else if (chunk < 25) { W = uw1; kbase = (chunk - 17) * 32; }
        else                 { W = uw2; kbase = (chunk - 25) * 32; }
        int k = kbase + (lane >> 4) * 8 + j;
        int n = ct * 16 + (lane & 15);
        frags[idx] = f2bf(W[k * 128 + n]);
    } else {  // uw3 [128][64]
        int rem = idx - FU3_OFF;
        int chunk = rem >> 11;
        int r = rem & 2047;
        int ct = r >> 9;
        int lane = (r >> 3) & 63;
        int j = r & 7;
        int k = chunk * 32 + (lane >> 4) * 8 + j;
        int n = ct * 16 + (lane & 15);
        frags[idx] = f2bf(uw3[k * 64 + n]);
    }
}

// ---------------------------------------------------------------------------
// MFMA helpers. acc init = column-broadcast bias.
// ---------------------------------------------------------------------------
template <int NCT>
__device__ __forceinline__ void bias_init(floatx4* acc,
                                          const float* __restrict__ bias, int lane) {
    int c = lane & 15;
#pragma unroll
    for (int ct = 0; ct < NCT; ct++) {
        float b = bias[ct * 16 + c];
        acc[ct][0] = b; acc[ct][1] = b; acc[ct][2] = b; acc[ct][3] = b;
    }
}

template <int NCH, int NCT>
__device__ __forceinline__ void mfma_layer(const unsigned short* Xl, int xs,
                                           const unsigned short* __restrict__ F,
                                           int lane, floatx4* acc) {
    int q = lane >> 4, c = lane & 15;
    const unsigned short* xrow = Xl + c * xs + q * 8;
    for (int k0 = 0; k0 < NCH; k0++) {
        short8 a = *(const short8*)(xrow + k0 * 32);
#pragma unroll
        for (int ct = 0; ct < NCT; ct++) {
            short8 b = *(const short8*)(F + ((k0 * NCT + ct) * 64 + lane) * 8);
            acc[ct] = __builtin_amdgcn_mfma_f32_16x16x32_bf16(a, b, acc[ct], 0, 0, 0);
        }
    }
}

// N-SPLIT variant: wave w owns col-stripe [32w, 32w+32) (ct pair {2w,2w+1})
// of ALL 64 block rows (4 row-tiles). One b-fragment load feeds 4 MFMAs ->
// block-wide b-fragment traffic drops 4x vs the M-split mfma_layer.
// Rows live tiled: row e at x1 + (e>>4)*16*XS1 + (e&15)*rstride.
template <int NCH>
__device__ __forceinline__ void mfma_nsplit(const unsigned short* x1, int rstride,
                                            const unsigned short* __restrict__ F,
                                            int lane, int w2,
                                            floatx4 acc[4][2]) {
    int q = lane >> 4, c = lane & 15;
    for (int k0 = 0; k0 < NCH; k0++) {
        short8 b0 = *(const short8*)(F + (((k0 * 8 + w2) * 64) + lane) * 8);
        short8 b1 = *(const short8*)(F + (((k0 * 8 + w2 + 1) * 64) + lane) * 8);
#pragma unroll
        for (int rt = 0; rt < 4; rt++) {
            short8 a = *(const short8*)(x1 + rt * (16 * XS1) + c * rstride
                                        + q * 8 + k0 * 32);
            acc[rt][0] = __builtin_amdgcn_mfma_f32_16x16x32_bf16(a, b0, acc[rt][0], 0, 0, 0);
            acc[rt][1] = __builtin_amdgcn_mfma_f32_16x16x32_bf16(a, b1, acc[rt][1], 0, 0, 0);
        }
    }
}

__device__ __forceinline__ void bias_init2(floatx4 acc[4][2],
                                           const float* __restrict__ bias,
                                           int lane, int w) {
    int c = lane & 15;
    float b0 = bias[w * 32 + c], b1 = bias[w * 32 + 16 + c];
#pragma unroll
    for (int rt = 0; rt < 4; rt++) {
        acc[rt][0][0] = b0; acc[rt][0][1] = b0; acc[rt][0][2] = b0; acc[rt][0][3] = b0;
        acc[rt][1][0] = b1; acc[rt][1][1] = b1; acc[rt][1][2] = b1; acc[rt][1][3] = b1;
    }
}

// gelu + packed-bf16 store of a wave's col-stripe into the tiled @HS layout.
__device__ __forceinline__ void epi2_store(floatx4 acc[4][2],
                                           unsigned short* x1, int lane, int w) {
    int q = lane >> 4, c = lane & 15;
#pragma unroll
    for (int rt = 0; rt < 4; rt++) {
        unsigned short* base = x1 + rt * (16 * XS1) + (q * 4) * HS + w * 32 + c;
#pragma unroll
        for (int ctl = 0; ctl < 2; ctl++) {
            f32x2 v01 = {acc[rt][ctl][0], acc[rt][ctl][1]};
            f32x2 v23 = {acc[rt][ctl][2], acc[rt][ctl][3]};
            v01 = gelu_pk(v01); v23 = gelu_pk(v23);
            unsigned int p01 = f2bf2(v01.x, v01.y), p23 = f2bf2(v23.x, v23.y);
            unsigned short* p = base + ctl * 16;
            p[0]      = (unsigned short)p01;
            p[HS]     = (unsigned short)(p01 >> 16);
            p[2 * HS] = (unsigned short)p23;
            p[3 * HS] = (unsigned short)(p23 >> 16);
        }
    }
}

// (opt) packed gelu + packed-bf16 store into an A-layout LDS tile.
// C layout: value (ct,i) at row (lane>>4)*4+i, col 16*ct+(lane&15).
template <bool GELU, int NCT>
__device__ __forceinline__ void epilogue_store(floatx4* acc,
                                               unsigned short* dst, int xs, int lane) {
    int q = lane >> 4, c = lane & 15;
    unsigned short* base = dst + (q * 4) * xs + c;
#pragma unroll
    for (int ct = 0; ct < NCT; ct++) {
        f32x2 v01 = {acc[ct][0], acc[ct][1]};
        f32x2 v23 = {acc[ct][2], acc[ct][3]};
        if (GELU) { v01 = gelu_pk(v01); v23 = gelu_pk(v23); }
        unsigned int p01 = f2bf2(v01.x, v01.y), p23 = f2bf2(v23.x, v23.y);
        unsigned short* p = base + ct * 16;
        p[0]      = (unsigned short)p01;
        p[xs]     = (unsigned short)(p01 >> 16);
        p[2 * xs] = (unsigned short)p23;
        p[3 * xs] = (unsigned short)(p23 >> 16);
    }
}

// ---------------------------------------------------------------------------
// LayerNorm (bf16 out) + global-mean partials (replicated atomics)
// + flow_dir normalize + degree
// ---------------------------------------------------------------------------
__global__ __launch_bounds__(256) void ln_count_kernel(
    const float* __restrict__ h, const float* __restrict__ ln_g,
    const float* __restrict__ ln_b, const float* __restrict__ flow_dir,
    const int* __restrict__ eidx, unsigned short* __restrict__ featb,
    float* __restrict__ gsum, float* __restrict__ u_out,
    int* __restrict__ deg_int) {
    int t = threadIdx.x;
    int ln = t >> 6;
    int c = t & 63;
    int n = blockIdx.x * 4 + ln;

    float x = h[n * CDIM + c];
    float s = x;
#pragma unroll
    for (int off = 32; off > 0; off >>= 1) s += __shfl_xor(s, off, 64);
    float mu = s * (1.0f / 64.0f);
    float d = x - mu;
    float v = d * d;
#pragma unroll
    for (int off = 32; off > 0; off >>= 1) v += __shfl_xor(v, off, 64);
    float rs = 1.0f / sqrtf(v * (1.0f / 64.0f) + 1e-5f);
    float f = d * rs * ln_g[c] + ln_b[c];
    featb[n * CDIM + c] = f2bf(f);

    __shared__ float fs[4][64];
    fs[ln][c] = f;
    __syncthreads();   // cross-wave reduction below (real dependency, keep)
    if (t < 64) {
        float p = fs[0][t] + fs[1][t] + fs[2][t] + fs[3][t];
        atomicAdd(&gsum[(blockIdx.x & (GSUM_REP - 1)) * 64 + t], p);
        int e = blockIdx.x * 64 + t;           // 12500*64 == N_EDGES
        atomicAdd(&deg_int[eidx[e]], 1);
    }
    if (blockIdx.x == 0 && t == 0) {
        float ux = flow_dir[0], uy = flow_dir[1], uz = flow_dir[2];
        float nrm = sqrtf(ux * ux + uy * uy + uz * uz) + 1e-8f;
        u_out[0] = ux / nrm;
        u_out[1] = uy / nrm;
        u_out[2] = uz / nrm;
    }
}

// ---------------------------------------------------------------------------
// Merged mid kernel: block 0 = exclusive prefix scan; block 1 = global MLP
// (first reducing the gsum replicas).
// ---------------------------------------------------------------------------
__global__ __launch_bounds__(1024) void mid_kernel(
    const int* __restrict__ deg_int, int* __restrict__ rowstart,
    int* __restrict__ cursor,
    const float* __restrict__ gsum,
    const float* __restrict__ glw1, const float* __restrict__ glb1,
    const float* __restrict__ glw2, const float* __restrict__ glb2,
    const float* __restrict__ glw3, const float* __restrict__ glb3,
    const float* __restrict__ res_scale,
    unsigned short* __restrict__ gctxb, float* __restrict__ tres) {
    int t = threadIdx.x;
    if (blockIdx.x == 0) {
        __shared__ int wsum[16];
        __shared__ int run;
        int wid = t >> 6, lane = t & 63;
        int4 vs[13];
#pragma unroll
        for (int chunk = 0; chunk < 13; chunk++) {
            int base = chunk * 4096 + t * 4;
            int4 v = {0, 0, 0, 0};
            if (base + 3 < N_NODES) {
                v = *(const int4*)(deg_int + base);
            } else {
                if (base < N_NODES) v.x = deg_int[base];
                if (base + 1 < N_NODES) v.y = deg_int[base + 1];
                if (base + 2 < N_NODES) v.z = deg_int[base + 2];
                if (base + 3 < N_NODES) v.w = deg_int[base + 3];
            }
            vs[chunk] = v;
        }
        if (t == 0) run = 0;
        __syncthreads();
#pragma unroll
        for (int chunk = 0; chunk < 13; chunk++) {
            int base = chunk * 4096 + t * 4;
            int4 v = vs[chunk];
            int s1 = v.x, s2 = s1 + v.y, s3 = s2 + v.z, s4 = s3 + v.w;
            int x = s4;
#pragma unroll
            for (int off = 1; off < 64; off <<= 1) {
                int y = __shfl_up(x, off, 64);
                if (lane >= off) x += y;
            }
            if (lane == 63) wsum[wid] = x;
            __syncthreads();
            if (t < 16) {
                int sv = wsum[t];
#pragma unroll
                for (int off = 1; off < 16; off <<= 1) {
                    int y = __shfl_up(sv, off, 16);
                    if (t >= off) sv += y;
                }
                wsum[t] = sv;
            }
            __syncthreads();
            int run_l = run;
            int wpre = (wid == 0) ? 0 : wsum[wid - 1];
            int toff = run_l + wpre + (x - s4);
            int e0 = toff, e1 = toff + s1, e2 = toff + s2, e3 = toff + s3;
            if (base <= N_NODES) rowstart[base] = e0;
            if (base + 1 <= N_NODES) rowstart[base + 1] = e1;
            if (base + 2 <= N_NODES) rowstart[base + 2] = e2;
            if (base + 3 <= N_NODES) rowstart[base + 3] = e3;
            if (base < N_NODES) cursor[base] = e0;
            if (base + 1 < N_NODES) cursor[base + 1] = e1;
            if (base + 2 < N_NODES) cursor[base + 2] = e2;
            if (base + 3 < N_NODES) cursor[base + 3] = e3;
            __syncthreads();
            if (t == 0) run = run_l + wsum[15];
            __syncthreads();
        }
    } else {
        __shared__ float a[64], b[64];
        float s = 0.0f;
        if (t < 64) {
            float acc = 0.0f;
            for (int r = 0; r < GSUM_REP; r++) acc += gsum[r * 64 + t];
            a[t] = acc * (1.0f / (float)N_NODES);
        }
        __syncthreads();
        if (t < 64) {
            s = glb1[t];
            for (int k = 0; k < 64; k++) s += a[k] * glw1[k * 64 + t];
            b[t] = gelu_fast(s);
        }
        __syncthreads();
        if (t < 64) {
            s = glb2[t];
            for (int k = 0; k < 64; k++) s += b[k] * glw2[k * 64 + t];
        }
        __syncthreads();
        if (t < 64) a[t] = gelu_fast(s);
        __syncthreads();
        if (t < 64) {
            s = glb3[t];
            for (int k = 0; k < 64; k++) s += a[k] * glw3[k * 64 + t];
            gctxb[t] = f2bf(s);
        }
        if (t == 0) *tres = tanhf(res_scale[0]);
    }
}

// ---------------------------------------------------------------------------
// Fused MFMA edge pipeline, N-SPLIT (R5/R6-verified): 64 edges/block, 4 waves;
// each wave owns a 32-col stripe of ALL 64 edges -> every B-fragment load
// feeds 4 MFMAs (4x b-traffic cut, R5: 300->250) + deferred cursor atomic +
// 6 blocks/CU (R6: 250->237, FETCH 85.9MB, no thrash).
//
// R7 delta: 7 blocks/CU. LDS 23040*7 = 161280 <= 163840 B fits; VGPR 40 <=
// 512/7 = 73. R6's 5->6 step was +5.5% at zero FETCH cost; same experiment
// one step further. Abort criterion: FETCH >= 110MB & dur >= 237 -> revert.
// ---------------------------------------------------------------------------
struct SmemE {
    unsigned short x1[64 * XS1];   // 21504 B, all pipeline stages live here
    float gatep[4][64];            // per-wave gate partials
    int pos[64];
    int rows[64];
};

__global__ __launch_bounds__(256, 7) void edge_kernel(
    const float* __restrict__ coords, const int* __restrict__ eidx,
    const unsigned short* __restrict__ featb, const float* __restrict__ u,
    const unsigned short* __restrict__ frags,
    const float* __restrict__ eb1, const float* __restrict__ eb2,
    const float* __restrict__ eb3,
    const float* __restrict__ egb, const float* __restrict__ gw2,
    const float* __restrict__ gb2,
    int* __restrict__ cursor, unsigned short* __restrict__ msg,
    float* __restrict__ agg, int use_msg) {
    __shared__ SmemE sm;
    int t = threadIdx.x;
    int wv = t >> 6;
    int lane = t & 63;
    int e0 = blockIdx.x * 64;
    int q = lane >> 4, c = lane & 15;
    int w2 = wv * 2;                      // this wave's ct stripe {w2, w2+1}

    int rowreg;                            // staged edge's row (sub==0 teams)
    {   // stage folded edge_input (bf16 copies, no cvt): 4 threads/edge
        int le = t >> 2, sub = t & 3;
        int e = e0 + le;
        int row = eidx[e];
        int col = eidx[N_EDGES + e];
        rowreg = row;
        const uint4* fi4 = (const uint4*)(featb + (long)row * CDIM);
        const uint4* fj4 = (const uint4*)(featb + (long)col * CDIM);
        unsigned short* xr = sm.x1 + le * XS1;
        *(uint4*)(xr + sub * 16) = fi4[sub * 2];
        *(uint4*)(xr + sub * 16 + 8) = fi4[sub * 2 + 1];
        *(uint4*)(xr + 64 + sub * 16) = fj4[sub * 2];
        *(uint4*)(xr + 64 + sub * 16 + 8) = fj4[sub * 2 + 1];
        ushort4 z = {0, 0, 0, 0};
        if (sub == 0) {
            sm.rows[le] = row;
            float xix = coords[row * 3], xiy = coords[row * 3 + 1], xiz = coords[row * 3 + 2];
            float xjx = coords[col * 3], xjy = coords[col * 3 + 1], xjz = coords[col * 3 + 2];
            float rx = xix - xjx, ry = xiy - xjy, rz = xiz - xjz;
            float ux = u[0], uy = u[1], uz = u[2];
            float4 sc;
            sc.x = rx * rx + ry * ry + rz * rz;
            sc.y = xix * ux + xiy * uy + xiz * uz;
            sc.z = xjx * ux + xjy * uy + xjz * uz;
            sc.w = rx * ux + ry * uy + rz * uz;
            *(ushort4*)(xr + 128) = pack4(sc);
        } else if (sub == 1) {
            *(ushort4*)(xr + 132) = z; *(ushort4*)(xr + 136) = z; *(ushort4*)(xr + 140) = z;
        } else if (sub == 2) {
            *(ushort4*)(xr + 144) = z; *(ushort4*)(xr + 148) = z;
        } else {
            *(ushort4*)(xr + 152) = z; *(ushort4*)(xr + 156) = z;
        }
    }
    __syncthreads();

    floatx4 acc[4][2];

    // L1 (folded, K=160): read all rows @XS1 (stripe cols) | B | write @HS
    bias_init2(acc, eb1, lane, wv);
    mfma_nsplit<5>(sm.x1, XS1, frags + F1_OFF, lane, w2, acc);
    __syncthreads();                       // all XS1 reads done before HS writes
    epi2_store(acc, sm.x1, lane, wv);
    __syncthreads();

    // L2: H1 -> H2 (in-place row-for-row @HS): read | B | write
    bias_init2(acc, eb2, lane, wv);
    mfma_nsplit<4>(sm.x1, HS, frags + F2_OFF, lane, w2, acc);
    __syncthreads();
    epi2_store(acc, sm.x1, lane, wv);
    __syncthreads();

    // Deferred CSR slot acquisition: issue the contended atomic NOW so its
    // latency hides under the gate+L3+store compute below. Result parked in
    // a VGPR; LDS publish happens right before the final barrier.
    int posreg = 0;
    if (use_msg && (t & 3) == 0) posreg = atomicAdd(&cursor[rowreg], 1);

    // Gate G1 stripe (composed ew3@gw1) -> per-edge partials -> gatep
    bias_init2(acc, egb, lane, wv);
    mfma_nsplit<4>(sm.x1, HS, frags + FG_OFF, lane, w2, acc);
    {
#pragma unroll
        for (int rt = 0; rt < 4; rt++) {
            float w2v0 = gw2[wv * 32 + c];
            float w2v1 = gw2[wv * 32 + 16 + c];
            f32x2 g01a = gelu_pk((f32x2){acc[rt][0][0], acc[rt][0][1]});
            f32x2 g23a = gelu_pk((f32x2){acc[rt][0][2], acc[rt][0][3]});
            f32x2 g01b = gelu_pk((f32x2){acc[rt][1][0], acc[rt][1][1]});
            f32x2 g23b = gelu_pk((f32x2){acc[rt][1][2], acc[rt][1][3]});
            float p[4];
            p[0] = g01a.x * w2v0 + g01b.x * w2v1;
            p[1] = g01a.y * w2v0 + g01b.y * w2v1;
            p[2] = g23a.x * w2v0 + g23b.x * w2v1;
            p[3] = g23a.y * w2v0 + g23b.y * w2v1;
#pragma unroll
            for (int i = 0; i < 4; i++) {
#pragma unroll
                for (int mask = 1; mask < 16; mask <<= 1)
                    p[i] += __shfl_xor(p[i], mask, 64);
            }
            if (c == 0) {
#pragma unroll
                for (int i = 0; i < 4; i++)
                    sm.gatep[wv][rt * 16 + q * 4 + i] = p[i];
            }
        }
    }

    // L3: H2 -> h3 stripe (fp32 regs; reads H2 like the gate did)
    floatx4 acch[4][2];
    bias_init2(acch, eb3, lane, wv);
    mfma_nsplit<4>(sm.x1, HS, frags + F3_OFF, lane, w2, acch);
    __syncthreads();   // gatep visible + all H2 reads done before store clobbers

    // finalize gates (redundant per-lane, broadcast LDS reads within 16-group)
    float gb = gb2[0];
    float g4[4][4];
#pragma unroll
    for (int rt = 0; rt < 4; rt++) {
#pragma unroll
        for (int i = 0; i < 4; i++) {
            int e = rt * 16 + q * 4 + i;
            float z = sm.gatep[0][e] + sm.gatep[1][e] + sm.gatep[2][e]
                    + sm.gatep[3][e] + gb;
            g4[rt][i] = 1.0f / (1.0f + __expf(-z));
        }
    }

    if (use_msg) {
        {   // scaled bf16 message stripe into tiled @HS layout from h3 regs
#pragma unroll
            for (int rt = 0; rt < 4; rt++) {
                unsigned short* base = sm.x1 + rt * (16 * XS1) + (q * 4) * HS
                                     + wv * 32 + c;
#pragma unroll
                for (int ctl = 0; ctl < 2; ctl++) {
                    unsigned int p01 = f2bf2(acch[rt][ctl][0] * g4[rt][0],
                                             acch[rt][ctl][1] * g4[rt][1]);
                    unsigned int p23 = f2bf2(acch[rt][ctl][2] * g4[rt][2],
                                             acch[rt][ctl][3] * g4[rt][3]);
                    unsigned short* p = base + ctl * 16;
                    p[0]      = (unsigned short)p01;
                    p[HS]     = (unsigned short)(p01 >> 16);
                    p[2 * HS] = (unsigned short)p23;
                    p[3 * HS] = (unsigned short)(p23 >> 16);
                }
            }
        }
        // publish the deferred CSR slots (atomic latency long since covered)
        if ((t & 3) == 0) sm.pos[t >> 2] = posreg;
        __syncthreads();
        {   // coalesced 256B-row stream to msg[pos[e]] (unchanged from R0)
            int le = t >> 2, sub = t & 3;
            long base = (long)sm.pos[le] * MCDIM;
            const unsigned short* src = sm.x1 + (le >> 4) * 16 * XS1 + (le & 15) * HS;
#pragma unroll
            for (int m = 0; m < 4; m++) {
                int off = m * 32 + sub * 8;
                *(short8*)(msg + base + off) = *(const short8*)(src + off);
            }
        }
    } else {
#pragma unroll
        for (int rt = 0; rt < 4; rt++) {
#pragma unroll
            for (int i = 0; i < 4; i++) {
                int row = sm.rows[rt * 16 + q * 4 + i];
                float* agr = agg + (long)row * MCDIM + wv * 32 + c;
#pragma unroll
                for (int ctl = 0; ctl < 2; ctl++)
                    atomicAdd(agr + ctl * 16, g4[rt][i] * acch[rt][ctl][i]);
            }
        }
    }
}

// ---------------------------------------------------------------------------
// Gather: one wave per node (fallback !use_msg path only — the msg-CSR path
// is fused into update_kernel).
// ---------------------------------------------------------------------------
__global__ __launch_bounds__(256) void gather_kernel(
    const int* __restrict__ rowstart, const unsigned short* __restrict__ msg,
    const float* __restrict__ agg, int use_msg,
    unsigned short* __restrict__ aggb) {
    int wv = threadIdx.x >> 6, lane = threadIdx.x & 63;
    int n = blockIdx.x * 4 + wv;
    if (n >= N_NODES) return;
    int rs = rowstart[n], re = rowstart[n + 1];
    int deg = re - rs;
    float a0 = 0.0f, a1 = 0.0f, a2 = 0.0f, a3 = 0.0f;
    if (use_msg) {
        const unsigned short* base = msg + (long)rs * MCDIM;
        int pairs = deg >> 1;
        for (int i = 0; i < pairs; i++) {
            uint2 v = *(const uint2*)(base + i * 256 + lane * 4);
            a0 += bf2f(v.x & 0xffffu); a1 += bf2f(v.x >> 16);
            a2 += bf2f(v.y & 0xffffu); a3 += bf2f(v.y >> 16);
        }
        if ((deg & 1) && lane < 32) {
            uint2 v = *(const uint2*)(base + (deg - 1) * MCDIM + lane * 4);
            a0 += bf2f(v.x & 0xffffu); a1 += bf2f(v.x >> 16);
            a2 += bf2f(v.y & 0xffffu); a3 += bf2f(v.y >> 16);
        }
        a0 += __shfl_xor(a0, 32, 64);
        a1 += __shfl_xor(a1, 32, 64);
        a2 += __shfl_xor(a2, 32, 64);
        a3 += __shfl_xor(a3, 32, 64);
    } else if (lane < 32) {
        const float4 v = *(const float4*)(agg + (long)n * MCDIM + lane * 4);
        a0 = v.x; a1 = v.y; a2 = v.z; a3 = v.w;
    }
    if (lane < 32) {
        float inv = 1.0f / fmaxf((float)deg, 1.0f);
        uint2 o;
        o.x = f2bf2(a0 * inv, a1 * inv);
        o.y = f2bf2(a2 * inv, a3 * inv);
        *(uint2*)(aggb + (long)n * MCDIM + lane * 4) = o;
    }
}

// ---------------------------------------------------------------------------
// MFMA node update WITH FUSED GATHER (use_msg path): each wave reduces the
// msg CSR rows of its own 16 nodes straight into its LDS staging slice —
// saves the aggb HBM round-trip (25.6 MB), one launch, and overlaps the
// msg-read memory phase with other blocks' MFMA compute instead of a strict
// gather-then-update serialization. Reduction math identical to
// gather_kernel (fp32 accumulate -> *inv -> f2bf2), so output bits match.
// 64 nodes/block, 4 blocks/CU.
// ---------------------------------------------------------------------------
struct SmemU {
    unsigned short ui[64 * UST];   // 33792 B, all stages live here
};

__global__ __launch_bounds__(256, 4) void update_kernel(
    const unsigned short* __restrict__ featb, const unsigned short* __restrict__ aggb,
    const int* __restrict__ rowstart, const unsigned short* __restrict__ msg,
    const unsigned short* __restrict__ gctxb, const float* __restrict__ tres,
    const unsigned short* __restrict__ frags,
    const float* __restrict__ ub1, const float* __restrict__ ub2,
    const float* __restrict__ ub3,
    float* __restrict__ out, int use_msg) {
    __shared__ SmemU sm;
    int t = threadIdx.x;
    int wv = t >> 6;
    int lane = t & 63;
    int n0 = blockIdx.x * 64;
    unsigned short* slice = sm.ui + wv * 16 * UST;   // wave-private

    {   // stage [feat | gctx] (+ aggb when pre-reduced): 4 threads/node
        int ln = t >> 2, sub = t & 3;
        int n = n0 + ln;
        unsigned short* ur = sm.ui + ln * UST;
        if (n < N_NODES) {
            const uint4* f4 = (const uint4*)(featb + (long)n * CDIM);
            *(uint4*)(ur + sub * 16) = f4[sub * 2];
            *(uint4*)(ur + sub * 16 + 8) = f4[sub * 2 + 1];
            if (!use_msg) {
                const uint4* a4 = (const uint4*)(aggb + (long)n * MCDIM);
                *(uint4*)(ur + 64 + sub * 32) = a4[sub * 4];
                *(uint4*)(ur + 64 + sub * 32 + 8) = a4[sub * 4 + 1];
                *(uint4*)(ur + 64 + sub * 32 + 16) = a4[sub * 4 + 2];
                *(uint4*)(ur + 64 + sub * 32 + 24) = a4[sub * 4 + 3];
            }
            const uint4* g4 = (const uint4*)gctxb;
            *(uint4*)(ur + 192 + sub * 16) = g4[sub * 2];
            *(uint4*)(ur + 192 + sub * 16 + 8) = g4[sub * 2 + 1];
        } else {
            uint4 z = {0, 0, 0, 0};
#pragma unroll
            for (int m = 0; m < 8; m++) *(uint4*)(ur + sub * 64 + m * 8) = z;
        }
    }

    if (use_msg) {   // fused gather: wave reduces its own slice's 16 nodes
        for (int ln2 = 0; ln2 < 16; ln2++) {
            int n = n0 + wv * 16 + ln2;
            if (n >= N_NODES) break;           // tail rows already zeroed
            int rs = rowstart[n], re = rowstart[n + 1];
            int deg = re - rs;
            float a0 = 0.0f, a1 = 0.0f, a2 = 0.0f, a3 = 0.0f;
            const unsigned short* basep = msg + (long)rs * MCDIM;
            int pairs = deg >> 1;
            for (int i = 0; i < pairs; i++) {
                uint2 v = *(const uint2*)(basep + i * 256 + lane * 4);
                a0 += bf2f(v.x & 0xffffu); a1 += bf2f(v.x >> 16);
                a2 += bf2f(v.y & 0xffffu); a3 += bf2f(v.y >> 16);
            }
            if ((deg & 1) && lane < 32) {
                uint2 v = *(const uint2*)(basep + (deg - 1) * MCDIM + lane * 4);
                a0 += bf2f(v.x & 0xffffu); a1 += bf2f(v.x >> 16);
                a2 += bf2f(v.y & 0xffffu); a3 += bf2f(v.y >> 16);
            }
            a0 += __shfl_xor(a0, 32, 64);
            a1 += __shfl_xor(a1, 32, 64);
            a2 += __shfl_xor(a2, 32, 64);
            a3 += __shfl_xor(a3, 32, 64);
            if (lane < 32) {
                float inv = 1.0f / fmaxf((float)deg, 1.0f);
                uint2 o;
                o.x = f2bf2(a0 * inv, a1 * inv);
                o.y = f2bf2(a2 * inv, a3 * inv);
                *(uint2*)(sm.ui + (wv * 16 + ln2) * UST + 64 + lane * 4) = o;
            }
        }
    }
    __syncthreads();

    floatx4 acc[8];
    bias_init<8>(acc, ub1, lane);
    mfma_layer<8, 8>(slice, UST, frags + FU1_OFF, lane, acc);
    epilogue_store<true, 8>(acc, slice, HS, lane);
    __syncthreads();

    bias_init<8>(acc, ub2, lane);
    mfma_layer<4, 8>(slice, HS, frags + FU2_OFF, lane, acc);
    epilogue_store<true, 8>(acc, slice, HS, lane);
    __syncthreads();

    floatx4 acc3[4];
    bias_init<4>(acc3, ub3, lane);
    mfma_layer<4, 4>(slice, HS, frags + FU3_OFF, lane, acc3);
    {
        int q = lane >> 4, c = lane & 15;
        float tr = *tres;
#pragma unroll
        for (int ct = 0; ct < 4; ct++) {
#pragma unroll
            for (int i = 0; i < 4; i++) {
                int n = n0 + wv * 16 + q * 4 + i;
                if (n < N_NODES) out[(long)n * CDIM + ct * 16 + c] = acc3[ct][i] * tr;
            }
        }
    }
}

// ---------------------------------------------------------------------------
extern "C" void kernel_launch(void* const* d_in, const int* in_sizes, int n_in,
                              void* d_out, int out_size, void* d_ws, size_t ws_size,
                              hipStream_t stream) {
    const float* coords = (const float*)d_in[0];
    const float* h = (const float*)d_in[1];
    const float* flow = (const float*)d_in[2];
    const int* eidx = (const int*)d_in[3];
    const float* ln_g = (const float*)d_in[4];
    const float* ln_b = (const float*)d_in[5];
    const float* ew1 = (const float*)d_in[6];
    const float* eb1 = (const float*)d_in[7];
    const float* ew2 = (const float*)d_in[8];
    const float* eb2 = (const float*)d_in[9];
    const float* ew3 = (const float*)d_in[10];
    const float* eb3 = (const float*)d_in[11];
    const float* gw1 = (const float*)d_in[12];
    const float* gb1 = (const float*)d_in[13];
    const float* gw2 = (const float*)d_in[14];
    const float* gb2 = (const float*)d_in[15];
    const float* glw1 = (const float*)d_in[16];
    const float* glb1 = (const float*)d_in[17];
    const float* glw2 = (const float*)d_in[18];
    const float* glb2 = (const float*)d_in[19];
    const float* glw3 = (const float*)d_in[20];
    const float* glb3 = (const float*)d_in[21];
    const float* uw1 = (const float*)d_in[22];
    const float* ub1 = (const float*)d_in[23];
    const float* uw2 = (const float*)d_in[24];
    const float* ub2 = (const float*)d_in[25];
    const float* uw3 = (const float*)d_in[26];
    const float* ub3 = (const float*)d_in[27];
    const float* res = (const float*)d_in[28];

    // ---- workspace carve-up ----
    char* base = (char*)d_ws;
    unsigned short* frags = (unsigned short*)base;                 // FRAG_TOTAL us
    unsigned short* featb = (unsigned short*)(base + FRAG_TOTAL * 2); // N*64 us
    unsigned short* aggb = featb + (size_t)N_NODES * CDIM;         // N*128 us
    unsigned short* gctxb = aggb + (size_t)N_NODES * MCDIM;        // 64 us
    float* gsum = (float*)(gctxb + 64);                            // 32*64
    float* u = gsum + GSUM_REP * 64;                               // 4
    float* tres = u + 4;                                           // 1
    float* egb = tres + 1;                                         // 128
    int* rowstart = (int*)(egb + 128);                             // N+1
    int* cursor = rowstart + (N_NODES + 1);                        // N
    int* deg_int = cursor + N_NODES;                               // N
    char* tail = (char*)(deg_int + N_NODES);
    tail = (char*)(((uintptr_t)tail + 255) & ~(uintptr_t)255);
    size_t head_bytes = (size_t)(tail - base);
    size_t msg_bytes = (size_t)N_EDGES * MCDIM * 2;                // 204.8 MB bf16
    int use_msg = (ws_size >= head_bytes + msg_bytes) ? 1 : 0;
    unsigned short* msg = (unsigned short*)tail;                   // CSR slots
    float* agg = (float*)tail;                                     // fallback

    if (!use_msg)
        hipMemsetAsync(agg, 0, (size_t)N_NODES * MCDIM * sizeof(float), stream);

    prep_frags<<<FRAG_TOTAL / 256, 256, 0, stream>>>(ew1, ew2, ew3, gw1,
                                                     eb3, gb1,
                                                     uw1, uw2, uw3, frags,
                                                     deg_int, gsum, egb);
    ln_count_kernel<<<N_NODES / 4, 256, 0, stream>>>(h, ln_g, ln_b, flow, eidx,
                                                     featb, gsum, u, deg_int);
    mid_kernel<<<2, 1024, 0, stream>>>(deg_int, rowstart, cursor, gsum,
                                       glw1, glb1, glw2, glb2, glw3, glb3,
                                       res, gctxb, tres);
    edge_kernel<<<N_EDGES / 64, 256, 0, stream>>>(coords, eidx, featb, u, frags,
                                                  eb1, eb2, eb3, egb, gw2, gb2,
                                                  cursor, msg, agg, use_msg);
    if (!use_msg)
        gather_kernel<<<(N_NODES + 3) / 4, 256, 0, stream>>>(rowstart, msg, agg,
                                                             use_msg, aggb);
    update_kernel<<<(N_NODES + 63) / 64, 256, 0, stream>>>(featb, aggb,
                                                           rowstart, msg,
                                                           gctxb, tres, frags,
                                                           ub1, ub2, ub3,
                                                           (float*)d_out, use_msg);
}

// Round 8
// 462.575 us; speedup vs baseline: 1.0404x; 1.0404x over previous
//
#include <hip/hip_runtime.h>
#include <hip/hip_bf16.h>
#include <math.h>

#define N_NODES 50000
#define N_EDGES 800000
#define CDIM 64
#define MCDIM 128
#define GSUM_REP 32   // gsum replication factor (atomic decontention)

// bf16 LDS strides (elements). Row stride in dwords must be == 4 (mod 8) so
// the 16-row A-fragment ds_read_b128 pattern lands 2 lanes/bank (free, m136).
#define XS1 168       // folded edge_input, K = 132 padded -> 160 (84 dw % 8 == 4)
#define HS  136       // hidden layers, K=128                (68 dw % 8 == 4)
#define UST 264       // update_input, K=256                (132 dw % 8 == 4)

typedef __attribute__((ext_vector_type(8))) short short8;
typedef __attribute__((ext_vector_type(4))) float floatx4;
typedef __attribute__((ext_vector_type(2))) float f32x2;

// A&S 7.1.27 erf (abs err 5e-4) gelu, scalar form (used in small kernels).
__device__ __forceinline__ float gelu_fast(float x) {
    float z = fabsf(x) * 0.70710678f;
    float w = fmaf(z, fmaf(z, fmaf(z, fmaf(z, 0.078108f, 0.000972f),
                                   0.230389f), 0.278393f), 1.0f);
    float w2 = w * w;
    float r = __builtin_amdgcn_rcpf(w2 * w2);
    float m = 0.5f * fabsf(x);
    return fmaf(-m, r, fmaf(0.5f, x, m));
}

// Packed-pair gelu: identical per-element math; float2 vector arithmetic lets
// LLVM emit dual-issue v_pk_{mul,add,fma}_f32. rcp stays scalar.
__device__ __forceinline__ f32x2 gelu_pk(f32x2 x) {
    f32x2 ax = __builtin_elementwise_abs(x);
    f32x2 z = ax * 0.70710678f;
    f32x2 w = z * (z * (z * (z * 0.078108f + 0.000972f) + 0.230389f)
                   + 0.278393f) + 1.0f;
    f32x2 w2 = w * w;
    f32x2 w4 = w2 * w2;
    f32x2 r;
    r.x = __builtin_amdgcn_rcpf(w4.x);
    r.y = __builtin_amdgcn_rcpf(w4.y);
    f32x2 m = 0.5f * ax;
    return 0.5f * x + m - m * r;
}

__device__ __forceinline__ unsigned short f2bf(float f) {  // RNE fp32->bf16
    unsigned int u = __float_as_uint(f);
    unsigned int r = u + 0x7fffu + ((u >> 16) & 1u);
    return (unsigned short)(r >> 16);
}
__device__ __forceinline__ float bf2f(unsigned int lo16) {
    return __uint_as_float(lo16 << 16);
}
// packed 2x fp32 -> bf16 pair (v_cvt_pk_bf16_f32 on gfx950)
__device__ __forceinline__ unsigned int f2bf2(float lo, float hi) {
    __hip_bfloat162 v = __float22bfloat162_rn(make_float2(lo, hi));
    union { __hip_bfloat162 b; unsigned int u; } cv;
    cv.b = v;
    return cv.u;
}
__device__ __forceinline__ ushort4 pack4(float4 v) {
    ushort4 r;
    r.x = f2bf(v.x); r.y = f2bf(v.y); r.z = f2bf(v.z); r.w = f2bf(v.w);
    return r;
}

// ---------------------------------------------------------------------------
// Weight fragment pre-swizzle. B-fragment for 16x16x32: lane l holds
// B[k = k0 + (l>>4)*8 + j][n = 16*ct + (l&15)], j=0..7 -> contiguous 16B/lane.
// ew1 is FOLDED: k<64 -> Wi+Wd ; 64..127 -> Wj-Wd ; 128..131 -> geo ; pad 160.
// FG chunk is COMPOSED: egw = ew3 @ gw1 (gate reads H2, H3 skips LDS).
// Also computes egb = eb3 @ gw1 + gb1 and zero-inits deg_int/gsum replicas.
// ---------------------------------------------------------------------------
#define F1_OFF 0               // folded ew1: 5 chunks (K=160), N=128
#define F2_OFF (5 * 4096)      // ew2: 4
#define F3_OFF (9 * 4096)      // ew3: 4
#define FG_OFF (13 * 4096)     // composed ew3@gw1: 4
#define FU1_OFF (17 * 4096)    // uw1: 8 (K=256)
#define FU2_OFF (25 * 4096)    // uw2: 4
#define FU3_OFF (29 * 4096)    // uw3: 4 chunks x 2048 (N=64)
#define FRAG_TOTAL (29 * 4096 + 4 * 2048)   // 126976 ushorts

__global__ __launch_bounds__(256) void prep_frags(
    const float* __restrict__ ew1, const float* __restrict__ ew2,
    const float* __restrict__ ew3, const float* __restrict__ gw1,
    const float* __restrict__ eb3, const float* __restrict__ gb1,
    const float* __restrict__ uw1, const float* __restrict__ uw2,
    const float* __restrict__ uw3, unsigned short* __restrict__ frags,
    int* __restrict__ deg_int, float* __restrict__ gsum,
    float* __restrict__ egb) {
    int idx = blockIdx.x * 256 + threadIdx.x;
    if (idx < N_NODES) deg_int[idx] = 0;
    if (idx < GSUM_REP * 64) gsum[idx] = 0.0f;
    if (idx < 128) {   // egb[n] = gb1[n] + eb3 . gw1[:,n]
        float s = gb1[idx];
        for (int jj = 0; jj < 128; jj++) s += eb3[jj] * gw1[jj * 128 + idx];
        egb[idx] = s;
    }
    if (idx >= FRAG_TOTAL) return;
    if (idx < F2_OFF) {  // folded ew1
        int chunk = idx >> 12;
        int rem = idx & 4095;
        int ct = rem >> 9;
        int lane = (rem >> 3) & 63;
        int j = rem & 7;
        int k = chunk * 32 + (lane >> 4) * 8 + j;
        int n = ct * 16 + (lane & 15);
        float v;
        if (k < 64)       v = ew1[k * 128 + n] + ew1[(128 + k) * 128 + n];
        else if (k < 128) v = ew1[k * 128 + n] - ew1[(64 + k) * 128 + n];
        else if (k < 132) v = ew1[(192 + k - 128) * 128 + n];
        else              v = 0.0f;
        frags[idx] = f2bf(v);
    } else if (idx >= FG_OFF && idx < FU1_OFF) {  // composed egw = ew3 @ gw1
        int chunk = idx >> 12;           // 13..16
        int rem = idx & 4095;
        int ct = rem >> 9;
        int lane = (rem >> 3) & 63;
        int j = rem & 7;
        int k = (chunk - 13) * 32 + (lane >> 4) * 8 + j;
        int n = ct * 16 + (lane & 15);
        float s = 0.0f;
        for (int jj = 0; jj < 128; jj++) s += ew3[k * 128 + jj] * gw1[jj * 128 + n];
        frags[idx] = f2bf(s);
    } else if (idx < FU3_OFF) {
        int chunk = idx >> 12;
        int rem = idx & 4095;
        int ct = rem >> 9;
        int lane = (rem >> 3) & 63;
        int j = rem & 7;
        const float* W; int kbase;
        if (chunk < 9)       { W = ew2; kbase = (chunk - 5) * 32; }
        else if (chunk < 13) { W = ew3; kbase = (chunk - 9) * 32; }
        else if (chunk < 25) { W = uw1; kbase = (chunk - 17) * 32; }
        else                 { W = uw2; kbase = (chunk - 25) * 32; }
        int k = kbase + (lane >> 4) * 8 + j;
        int n = ct * 16 + (lane & 15);
        frags[idx] = f2bf(W[k * 128 + n]);
    } else {  // uw3 [128][64]
        int rem = idx - FU3_OFF;
        int chunk = rem >> 11;
        int r = rem & 2047;
        int ct = r >> 9;
        int lane = (r >> 3) & 63;
        int j = r & 7;
        int k = chunk * 32 + (lane >> 4) * 8 + j;
        int n = ct * 16 + (lane & 15);
        frags[idx] = f2bf(uw3[k * 64 + n]);
    }
}

// ---------------------------------------------------------------------------
// MFMA helpers. acc init = column-broadcast bias.
// ---------------------------------------------------------------------------
template <int NCT>
__device__ __forceinline__ void bias_init(floatx4* acc,
                                          const float* __restrict__ bias, int lane) {
    int c = lane & 15;
#pragma unroll
    for (int ct = 0; ct < NCT; ct++) {
        float b = bias[ct * 16 + c];
        acc[ct][0] = b; acc[ct][1] = b; acc[ct][2] = b; acc[ct][3] = b;
    }
}

template <int NCH, int NCT>
__device__ __forceinline__ void mfma_layer(const unsigned short* Xl, int xs,
                                           const unsigned short* __restrict__ F,
                                           int lane, floatx4* acc) {
    int q = lane >> 4, c = lane & 15;
    const unsigned short* xrow = Xl + c * xs + q * 8;
    for (int k0 = 0; k0 < NCH; k0++) {
        short8 a = *(const short8*)(xrow + k0 * 32);
#pragma unroll
        for (int ct = 0; ct < NCT; ct++) {
            short8 b = *(const short8*)(F + ((k0 * NCT + ct) * 64 + lane) * 8);
            acc[ct] = __builtin_amdgcn_mfma_f32_16x16x32_bf16(a, b, acc[ct], 0, 0, 0);
        }
    }
}

// N-SPLIT: wave w owns col-stripe [32w, 32w+32) (ct pair {2w,2w+1}) of ALL
// 64 block rows (4 row-tiles). One b-fragment load feeds 4 MFMAs -> block
// b-fragment traffic drops 4x vs the M-split mfma_layer (R5-verified).
// Rows live tiled: row r at x1 + (r>>4)*tilestride + (r&15)*rstride.
template <int NCH>
__device__ __forceinline__ void mfma_nsplit(const unsigned short* x1,
                                            int tilestride, int rstride,
                                            const unsigned short* __restrict__ F,
                                            int lane, int w2,
                                            floatx4 acc[4][2]) {
    int q = lane >> 4, c = lane & 15;
    for (int k0 = 0; k0 < NCH; k0++) {
        short8 b0 = *(const short8*)(F + (((k0 * 8 + w2) * 64) + lane) * 8);
        short8 b1 = *(const short8*)(F + (((k0 * 8 + w2 + 1) * 64) + lane) * 8);
#pragma unroll
        for (int rt = 0; rt < 4; rt++) {
            short8 a = *(const short8*)(x1 + rt * tilestride + c * rstride
                                        + q * 8 + k0 * 32);
            acc[rt][0] = __builtin_amdgcn_mfma_f32_16x16x32_bf16(a, b0, acc[rt][0], 0, 0, 0);
            acc[rt][1] = __builtin_amdgcn_mfma_f32_16x16x32_bf16(a, b1, acc[rt][1], 0, 0, 0);
        }
    }
}

__device__ __forceinline__ void bias_init2(floatx4 acc[4][2],
                                           const float* __restrict__ bias,
                                           int lane, int w) {
    int c = lane & 15;
    float b0 = bias[w * 32 + c], b1 = bias[w * 32 + 16 + c];
#pragma unroll
    for (int rt = 0; rt < 4; rt++) {
        acc[rt][0][0] = b0; acc[rt][0][1] = b0; acc[rt][0][2] = b0; acc[rt][0][3] = b0;
        acc[rt][1][0] = b1; acc[rt][1][1] = b1; acc[rt][1][2] = b1; acc[rt][1][3] = b1;
    }
}

// gelu + packed-bf16 store of a wave's col-stripe into the tiled @HS layout.
__device__ __forceinline__ void epi2_store(floatx4 acc[4][2],
                                           unsigned short* x1, int tilestride,
                                           int lane, int w) {
    int q = lane >> 4, c = lane & 15;
#pragma unroll
    for (int rt = 0; rt < 4; rt++) {
        unsigned short* base = x1 + rt * tilestride + (q * 4) * HS + w * 32 + c;
#pragma unroll
        for (int ctl = 0; ctl < 2; ctl++) {
            f32x2 v01 = {acc[rt][ctl][0], acc[rt][ctl][1]};
            f32x2 v23 = {acc[rt][ctl][2], acc[rt][ctl][3]};
            v01 = gelu_pk(v01); v23 = gelu_pk(v23);
            unsigned int p01 = f2bf2(v01.x, v01.y), p23 = f2bf2(v23.x, v23.y);
            unsigned short* p = base + ctl * 16;
            p[0]      = (unsigned short)p01;
            p[HS]     = (unsigned short)(p01 >> 16);
            p[2 * HS] = (unsigned short)p23;
            p[3 * HS] = (unsigned short)(p23 >> 16);
        }
    }
}

// ---------------------------------------------------------------------------
// LayerNorm (bf16 out) + global-mean partials (replicated atomics)
// + flow_dir normalize + degree
// ---------------------------------------------------------------------------
__global__ __launch_bounds__(256) void ln_count_kernel(
    const float* __restrict__ h, const float* __restrict__ ln_g,
    const float* __restrict__ ln_b, const float* __restrict__ flow_dir,
    const int* __restrict__ eidx, unsigned short* __restrict__ featb,
    float* __restrict__ gsum, float* __restrict__ u_out,
    int* __restrict__ deg_int) {
    int t = threadIdx.x;
    int ln = t >> 6;
    int c = t & 63;
    int n = blockIdx.x * 4 + ln;

    float x = h[n * CDIM + c];
    float s = x;
#pragma unroll
    for (int off = 32; off > 0; off >>= 1) s += __shfl_xor(s, off, 64);
    float mu = s * (1.0f / 64.0f);
    float d = x - mu;
    float v = d * d;
#pragma unroll
    for (int off = 32; off > 0; off >>= 1) v += __shfl_xor(v, off, 64);
    float rs = 1.0f / sqrtf(v * (1.0f / 64.0f) + 1e-5f);
    float f = d * rs * ln_g[c] + ln_b[c];
    featb[n * CDIM + c] = f2bf(f);

    __shared__ float fs[4][64];
    fs[ln][c] = f;
    __syncthreads();   // cross-wave reduction below (real dependency, keep)
    if (t < 64) {
        float p = fs[0][t] + fs[1][t] + fs[2][t] + fs[3][t];
        atomicAdd(&gsum[(blockIdx.x & (GSUM_REP - 1)) * 64 + t], p);
        int e = blockIdx.x * 64 + t;           // 12500*64 == N_EDGES
        atomicAdd(&deg_int[eidx[e]], 1);
    }
    if (blockIdx.x == 0 && t == 0) {
        float ux = flow_dir[0], uy = flow_dir[1], uz = flow_dir[2];
        float nrm = sqrtf(ux * ux + uy * uy + uz * uz) + 1e-8f;
        u_out[0] = ux / nrm;
        u_out[1] = uy / nrm;
        u_out[2] = uz / nrm;
    }
}

// ---------------------------------------------------------------------------
// Merged mid kernel: block 0 = exclusive prefix scan; block 1 = global MLP
// (first reducing the gsum replicas).
// ---------------------------------------------------------------------------
__global__ __launch_bounds__(1024) void mid_kernel(
    const int* __restrict__ deg_int, int* __restrict__ rowstart,
    int* __restrict__ cursor,
    const float* __restrict__ gsum,
    const float* __restrict__ glw1, const float* __restrict__ glb1,
    const float* __restrict__ glw2, const float* __restrict__ glb2,
    const float* __restrict__ glw3, const float* __restrict__ glb3,
    const float* __restrict__ res_scale,
    unsigned short* __restrict__ gctxb, float* __restrict__ tres) {
    int t = threadIdx.x;
    if (blockIdx.x == 0) {
        __shared__ int wsum[16];
        __shared__ int run;
        int wid = t >> 6, lane = t & 63;
        int4 vs[13];
#pragma unroll
        for (int chunk = 0; chunk < 13; chunk++) {
            int base = chunk * 4096 + t * 4;
            int4 v = {0, 0, 0, 0};
            if (base + 3 < N_NODES) {
                v = *(const int4*)(deg_int + base);
            } else {
                if (base < N_NODES) v.x = deg_int[base];
                if (base + 1 < N_NODES) v.y = deg_int[base + 1];
                if (base + 2 < N_NODES) v.z = deg_int[base + 2];
                if (base + 3 < N_NODES) v.w = deg_int[base + 3];
            }
            vs[chunk] = v;
        }
        if (t == 0) run = 0;
        __syncthreads();
#pragma unroll
        for (int chunk = 0; chunk < 13; chunk++) {
            int base = chunk * 4096 + t * 4;
            int4 v = vs[chunk];
            int s1 = v.x, s2 = s1 + v.y, s3 = s2 + v.z, s4 = s3 + v.w;
            int x = s4;
#pragma unroll
            for (int off = 1; off < 64; off <<= 1) {
                int y = __shfl_up(x, off, 64);
                if (lane >= off) x += y;
            }
            if (lane == 63) wsum[wid] = x;
            __syncthreads();
            if (t < 16) {
                int sv = wsum[t];
#pragma unroll
                for (int off = 1; off < 16; off <<= 1) {
                    int y = __shfl_up(sv, off, 16);
                    if (t >= off) sv += y;
                }
                wsum[t] = sv;
            }
            __syncthreads();
            int run_l = run;
            int wpre = (wid == 0) ? 0 : wsum[wid - 1];
            int toff = run_l + wpre + (x - s4);
            int e0 = toff, e1 = toff + s1, e2 = toff + s2, e3 = toff + s3;
            if (base <= N_NODES) rowstart[base] = e0;
            if (base + 1 <= N_NODES) rowstart[base + 1] = e1;
            if (base + 2 <= N_NODES) rowstart[base + 2] = e2;
            if (base + 3 <= N_NODES) rowstart[base + 3] = e3;
            if (base < N_NODES) cursor[base] = e0;
            if (base + 1 < N_NODES) cursor[base + 1] = e1;
            if (base + 2 < N_NODES) cursor[base + 2] = e2;
            if (base + 3 < N_NODES) cursor[base + 3] = e3;
            __syncthreads();
            if (t == 0) run = run_l + wsum[15];
            __syncthreads();
        }
    } else {
        __shared__ float a[64], b[64];
        float s = 0.0f;
        if (t < 64) {
            float acc = 0.0f;
            for (int r = 0; r < GSUM_REP; r++) acc += gsum[r * 64 + t];
            a[t] = acc * (1.0f / (float)N_NODES);
        }
        __syncthreads();
        if (t < 64) {
            s = glb1[t];
            for (int k = 0; k < 64; k++) s += a[k] * glw1[k * 64 + t];
            b[t] = gelu_fast(s);
        }
        __syncthreads();
        if (t < 64) {
            s = glb2[t];
            for (int k = 0; k < 64; k++) s += b[k] * glw2[k * 64 + t];
        }
        __syncthreads();
        if (t < 64) a[t] = gelu_fast(s);
        __syncthreads();
        if (t < 64) {
            s = glb3[t];
            for (int k = 0; k < 64; k++) s += a[k] * glw3[k * 64 + t];
            gctxb[t] = f2bf(s);
        }
        if (t == 0) *tres = tanhf(res_scale[0]);
    }
}

// ---------------------------------------------------------------------------
// Fused MFMA edge pipeline, N-SPLIT (R6-verified config, reverted from R7's
// failed 7-block experiment): 64 edges/block, 4 waves; each wave owns a
// 32-col stripe of ALL 64 edges -> every B-fragment load feeds 4 MFMAs
// (R5: 300->250) + deferred cursor atomic + 6 blocks/CU (R6: 250->237,
// FETCH 85.9MB). R7 proved 7 blocks overflows L2 (FETCH 149MB, WRITE 325MB,
// dur 239) -> 6 is the confirmed optimum.
// ---------------------------------------------------------------------------
struct SmemE {
    unsigned short x1[64 * XS1];   // 21504 B, all pipeline stages live here
    float gatep[4][64];            // per-wave gate partials
    int pos[64];
    int rows[64];
};

__global__ __launch_bounds__(256, 6) void edge_kernel(
    const float* __restrict__ coords, const int* __restrict__ eidx,
    const unsigned short* __restrict__ featb, const float* __restrict__ u,
    const unsigned short* __restrict__ frags,
    const float* __restrict__ eb1, const float* __restrict__ eb2,
    const float* __restrict__ eb3,
    const float* __restrict__ egb, const float* __restrict__ gw2,
    const float* __restrict__ gb2,
    int* __restrict__ cursor, unsigned short* __restrict__ msg,
    float* __restrict__ agg, int use_msg) {
    __shared__ SmemE sm;
    int t = threadIdx.x;
    int wv = t >> 6;
    int lane = t & 63;
    int e0 = blockIdx.x * 64;
    int q = lane >> 4, c = lane & 15;
    int w2 = wv * 2;                      // this wave's ct stripe {w2, w2+1}

    int rowreg;                            // staged edge's row (sub==0 teams)
    {   // stage folded edge_input (bf16 copies, no cvt): 4 threads/edge
        int le = t >> 2, sub = t & 3;
        int e = e0 + le;
        int row = eidx[e];
        int col = eidx[N_EDGES + e];
        rowreg = row;
        const uint4* fi4 = (const uint4*)(featb + (long)row * CDIM);
        const uint4* fj4 = (const uint4*)(featb + (long)col * CDIM);
        unsigned short* xr = sm.x1 + le * XS1;
        *(uint4*)(xr + sub * 16) = fi4[sub * 2];
        *(uint4*)(xr + sub * 16 + 8) = fi4[sub * 2 + 1];
        *(uint4*)(xr + 64 + sub * 16) = fj4[sub * 2];
        *(uint4*)(xr + 64 + sub * 16 + 8) = fj4[sub * 2 + 1];
        ushort4 z = {0, 0, 0, 0};
        if (sub == 0) {
            sm.rows[le] = row;
            float xix = coords[row * 3], xiy = coords[row * 3 + 1], xiz = coords[row * 3 + 2];
            float xjx = coords[col * 3], xjy = coords[col * 3 + 1], xjz = coords[col * 3 + 2];
            float rx = xix - xjx, ry = xiy - xjy, rz = xiz - xjz;
            float ux = u[0], uy = u[1], uz = u[2];
            float4 sc;
            sc.x = rx * rx + ry * ry + rz * rz;
            sc.y = xix * ux + xiy * uy + xiz * uz;
            sc.z = xjx * ux + xjy * uy + xjz * uz;
            sc.w = rx * ux + ry * uy + rz * uz;
            *(ushort4*)(xr + 128) = pack4(sc);
        } else if (sub == 1) {
            *(ushort4*)(xr + 132) = z; *(ushort4*)(xr + 136) = z; *(ushort4*)(xr + 140) = z;
        } else if (sub == 2) {
            *(ushort4*)(xr + 144) = z; *(ushort4*)(xr + 148) = z;
        } else {
            *(ushort4*)(xr + 152) = z; *(ushort4*)(xr + 156) = z;
        }
    }
    __syncthreads();

    floatx4 acc[4][2];

    // L1 (folded, K=160): read all rows @XS1 (stripe cols) | B | write @HS
    bias_init2(acc, eb1, lane, wv);
    mfma_nsplit<5>(sm.x1, 16 * XS1, XS1, frags + F1_OFF, lane, w2, acc);
    __syncthreads();                       // all XS1 reads done before HS writes
    epi2_store(acc, sm.x1, 16 * XS1, lane, wv);
    __syncthreads();

    // L2: H1 -> H2 (in-place row-for-row @HS): read | B | write
    bias_init2(acc, eb2, lane, wv);
    mfma_nsplit<4>(sm.x1, 16 * XS1, HS, frags + F2_OFF, lane, w2, acc);
    __syncthreads();
    epi2_store(acc, sm.x1, 16 * XS1, lane, wv);
    __syncthreads();

    // Deferred CSR slot acquisition: issue the contended atomic NOW so its
    // latency hides under the gate+L3+store compute below. Result parked in
    // a VGPR; LDS publish happens right before the final barrier.
    int posreg = 0;
    if (use_msg && (t & 3) == 0) posreg = atomicAdd(&cursor[rowreg], 1);

    // Gate G1 stripe (composed ew3@gw1) -> per-edge partials -> gatep
    bias_init2(acc, egb, lane, wv);
    mfma_nsplit<4>(sm.x1, 16 * XS1, HS, frags + FG_OFF, lane, w2, acc);
    {
#pragma unroll
        for (int rt = 0; rt < 4; rt++) {
            float w2v0 = gw2[wv * 32 + c];
            float w2v1 = gw2[wv * 32 + 16 + c];
            f32x2 g01a = gelu_pk((f32x2){acc[rt][0][0], acc[rt][0][1]});
            f32x2 g23a = gelu_pk((f32x2){acc[rt][0][2], acc[rt][0][3]});
            f32x2 g01b = gelu_pk((f32x2){acc[rt][1][0], acc[rt][1][1]});
            f32x2 g23b = gelu_pk((f32x2){acc[rt][1][2], acc[rt][1][3]});
            float p[4];
            p[0] = g01a.x * w2v0 + g01b.x * w2v1;
            p[1] = g01a.y * w2v0 + g01b.y * w2v1;
            p[2] = g23a.x * w2v0 + g23b.x * w2v1;
            p[3] = g23a.y * w2v0 + g23b.y * w2v1;
#pragma unroll
            for (int i = 0; i < 4; i++) {
#pragma unroll
                for (int mask = 1; mask < 16; mask <<= 1)
                    p[i] += __shfl_xor(p[i], mask, 64);
            }
            if (c == 0) {
#pragma unroll
                for (int i = 0; i < 4; i++)
                    sm.gatep[wv][rt * 16 + q * 4 + i] = p[i];
            }
        }
    }

    // L3: H2 -> h3 stripe (fp32 regs; reads H2 like the gate did)
    floatx4 acch[4][2];
    bias_init2(acch, eb3, lane, wv);
    mfma_nsplit<4>(sm.x1, 16 * XS1, HS, frags + F3_OFF, lane, w2, acch);
    __syncthreads();   // gatep visible + all H2 reads done before store clobbers

    // finalize gates (redundant per-lane, broadcast LDS reads within 16-group)
    float gb = gb2[0];
    float g4[4][4];
#pragma unroll
    for (int rt = 0; rt < 4; rt++) {
#pragma unroll
        for (int i = 0; i < 4; i++) {
            int e = rt * 16 + q * 4 + i;
            float z = sm.gatep[0][e] + sm.gatep[1][e] + sm.gatep[2][e]
                    + sm.gatep[3][e] + gb;
            g4[rt][i] = 1.0f / (1.0f + __expf(-z));
        }
    }

    if (use_msg) {
        {   // scaled bf16 message stripe into tiled @HS layout from h3 regs
#pragma unroll
            for (int rt = 0; rt < 4; rt++) {
                unsigned short* base = sm.x1 + rt * (16 * XS1) + (q * 4) * HS
                                     + wv * 32 + c;
#pragma unroll
                for (int ctl = 0; ctl < 2; ctl++) {
                    unsigned int p01 = f2bf2(acch[rt][ctl][0] * g4[rt][0],
                                             acch[rt][ctl][1] * g4[rt][1]);
                    unsigned int p23 = f2bf2(acch[rt][ctl][2] * g4[rt][2],
                                             acch[rt][ctl][3] * g4[rt][3]);
                    unsigned short* p = base + ctl * 16;
                    p[0]      = (unsigned short)p01;
                    p[HS]     = (unsigned short)(p01 >> 16);
                    p[2 * HS] = (unsigned short)p23;
                    p[3 * HS] = (unsigned short)(p23 >> 16);
                }
            }
        }
        // publish the deferred CSR slots (atomic latency long since covered)
        if ((t & 3) == 0) sm.pos[t >> 2] = posreg;
        __syncthreads();
        {   // coalesced 256B-row stream to msg[pos[e]] (unchanged from R0)
            int le = t >> 2, sub = t & 3;
            long base = (long)sm.pos[le] * MCDIM;
            const unsigned short* src = sm.x1 + (le >> 4) * 16 * XS1 + (le & 15) * HS;
#pragma unroll
            for (int m = 0; m < 4; m++) {
                int off = m * 32 + sub * 8;
                *(short8*)(msg + base + off) = *(const short8*)(src + off);
            }
        }
    } else {
#pragma unroll
        for (int rt = 0; rt < 4; rt++) {
#pragma unroll
            for (int i = 0; i < 4; i++) {
                int row = sm.rows[rt * 16 + q * 4 + i];
                float* agr = agg + (long)row * MCDIM + wv * 32 + c;
#pragma unroll
                for (int ctl = 0; ctl < 2; ctl++)
                    atomicAdd(agr + ctl * 16, g4[rt][i] * acch[rt][ctl][i]);
            }
        }
    }
}

// ---------------------------------------------------------------------------
// Gather: one wave per node; each iteration loads 512B (2 msg rows).
// R8: unrolled x2 with independent accumulator sets -> 1KB in flight per
// wave, doubling MLP for the latency-bound dependent-accumulate loop.
// ---------------------------------------------------------------------------
__global__ __launch_bounds__(256) void gather_kernel(
    const int* __restrict__ rowstart, const unsigned short* __restrict__ msg,
    const float* __restrict__ agg, int use_msg,
    unsigned short* __restrict__ aggb) {
    int wv = threadIdx.x >> 6, lane = threadIdx.x & 63;
    int n = blockIdx.x * 4 + wv;
    if (n >= N_NODES) return;
    int rs = rowstart[n], re = rowstart[n + 1];
    int deg = re - rs;
    float a0 = 0.0f, a1 = 0.0f, a2 = 0.0f, a3 = 0.0f;
    if (use_msg) {
        const unsigned short* base = msg + (long)rs * MCDIM;
        int pairs = deg >> 1;
        float b0 = 0.0f, b1 = 0.0f, b2 = 0.0f, b3 = 0.0f;
        int i = 0;
        for (; i + 1 < pairs; i += 2) {
            uint2 v = *(const uint2*)(base + i * 256 + lane * 4);
            uint2 w = *(const uint2*)(base + (i + 1) * 256 + lane * 4);
            a0 += bf2f(v.x & 0xffffu); a1 += bf2f(v.x >> 16);
            a2 += bf2f(v.y & 0xffffu); a3 += bf2f(v.y >> 16);
            b0 += bf2f(w.x & 0xffffu); b1 += bf2f(w.x >> 16);
            b2 += bf2f(w.y & 0xffffu); b3 += bf2f(w.y >> 16);
        }
        if (i < pairs) {
            uint2 v = *(const uint2*)(base + i * 256 + lane * 4);
            a0 += bf2f(v.x & 0xffffu); a1 += bf2f(v.x >> 16);
            a2 += bf2f(v.y & 0xffffu); a3 += bf2f(v.y >> 16);
        }
        a0 += b0; a1 += b1; a2 += b2; a3 += b3;
        if ((deg & 1) && lane < 32) {
            uint2 v = *(const uint2*)(base + (deg - 1) * MCDIM + lane * 4);
            a0 += bf2f(v.x & 0xffffu); a1 += bf2f(v.x >> 16);
            a2 += bf2f(v.y & 0xffffu); a3 += bf2f(v.y >> 16);
        }
        a0 += __shfl_xor(a0, 32, 64);
        a1 += __shfl_xor(a1, 32, 64);
        a2 += __shfl_xor(a2, 32, 64);
        a3 += __shfl_xor(a3, 32, 64);
    } else if (lane < 32) {
        const float4 v = *(const float4*)(agg + (long)n * MCDIM + lane * 4);
        a0 = v.x; a1 = v.y; a2 = v.z; a3 = v.w;
    }
    if (lane < 32) {
        float inv = 1.0f / fmaxf((float)deg, 1.0f);
        uint2 o;
        o.x = f2bf2(a0 * inv, a1 * inv);
        o.y = f2bf2(a2 * inv, a3 * inv);
        *(uint2*)(aggb + (long)n * MCDIM + lane * 4) = o;
    }
}

// ---------------------------------------------------------------------------
// MFMA node update, N-SPLIT (R8 — same transformation that won R5 on edge):
// update still used M-split, so all 4 waves redundantly streamed every
// B-fragment (~458 KB/block, 358 MB total of L2 b-reads). Now wave w owns
// col-stripe [32w,32w+32) of all 64 node rows for L1/L2 (16-col stripe for
// the N=64 L3) -> b-traffic /4 at identical MFMA work.
// Layouts: stage rows at n*UST (uniform; tile rt base = rt*16*UST);
// H1/H2 tiled: row r at (r>>4)*(16*UST) + (r&15)*HS (edge-verified form).
// Cross-wave in-place rewrite -> read | barrier | write per layer.
// L3 output written straight to global (stripe cols, coalesced 64B runs).
// 64 nodes/block, 4 blocks/CU (LDS 33792B).
// ---------------------------------------------------------------------------
struct SmemU {
    unsigned short ui[64 * UST];   // 33792 B, all stages live here
};

__global__ __launch_bounds__(256, 4) void update_kernel(
    const unsigned short* __restrict__ featb, const unsigned short* __restrict__ aggb,
    const unsigned short* __restrict__ gctxb, const float* __restrict__ tres,
    const unsigned short* __restrict__ frags,
    const float* __restrict__ ub1, const float* __restrict__ ub2,
    const float* __restrict__ ub3,
    float* __restrict__ out) {
    __shared__ SmemU sm;
    int t = threadIdx.x;
    int wv = t >> 6;
    int lane = t & 63;
    int n0 = blockIdx.x * 64;
    int q = lane >> 4, c = lane & 15;
    int w2 = wv * 2;

    {   // stage [feat | agg | gctx] (all bf16 copies): 4 threads/node
        int ln = t >> 2, sub = t & 3;
        int n = n0 + ln;
        unsigned short* ur = sm.ui + ln * UST;
        if (n < N_NODES) {
            const uint4* f4 = (const uint4*)(featb + (long)n * CDIM);
            *(uint4*)(ur + sub * 16) = f4[sub * 2];
            *(uint4*)(ur + sub * 16 + 8) = f4[sub * 2 + 1];
            const uint4* a4 = (const uint4*)(aggb + (long)n * MCDIM);
            *(uint4*)(ur + 64 + sub * 32) = a4[sub * 4];
            *(uint4*)(ur + 64 + sub * 32 + 8) = a4[sub * 4 + 1];
            *(uint4*)(ur + 64 + sub * 32 + 16) = a4[sub * 4 + 2];
            *(uint4*)(ur + 64 + sub * 32 + 24) = a4[sub * 4 + 3];
            const uint4* g4 = (const uint4*)gctxb;
            *(uint4*)(ur + 192 + sub * 16) = g4[sub * 2];
            *(uint4*)(ur + 192 + sub * 16 + 8) = g4[sub * 2 + 1];
        } else {
            uint4 z = {0, 0, 0, 0};
#pragma unroll
            for (int m = 0; m < 8; m++) *(uint4*)(ur + sub * 64 + m * 8) = z;
        }
    }
    __syncthreads();

    floatx4 acc[4][2];

    // L1 (K=256): read stage @ (16*UST, UST) | barrier | write H1 tiled @HS
    bias_init2(acc, ub1, lane, wv);
    mfma_nsplit<8>(sm.ui, 16 * UST, UST, frags + FU1_OFF, lane, w2, acc);
    __syncthreads();
    epi2_store(acc, sm.ui, 16 * UST, lane, wv);
    __syncthreads();

    // L2: H1 -> H2 in-place tiled @HS
    bias_init2(acc, ub2, lane, wv);
    mfma_nsplit<4>(sm.ui, 16 * UST, HS, frags + FU2_OFF, lane, w2, acc);
    __syncthreads();
    epi2_store(acc, sm.ui, 16 * UST, lane, wv);
    __syncthreads();

    // L3 (N=64): wave owns single 16-col stripe ct = wv; FU3 chunks are 2048
    floatx4 acc3[4];
    {
        float b = ub3[wv * 16 + c];
#pragma unroll
        for (int rt = 0; rt < 4; rt++) {
            acc3[rt][0] = b; acc3[rt][1] = b; acc3[rt][2] = b; acc3[rt][3] = b;
        }
        for (int k0 = 0; k0 < 4; k0++) {
            short8 bf = *(const short8*)(frags + FU3_OFF + k0 * 2048
                                         + wv * 512 + lane * 8);
#pragma unroll
            for (int rt = 0; rt < 4; rt++) {
                short8 a = *(const short8*)(sm.ui + rt * (16 * UST) + c * HS
                                            + q * 8 + k0 * 32);
                acc3[rt] = __builtin_amdgcn_mfma_f32_16x16x32_bf16(a, bf, acc3[rt], 0, 0, 0);
            }
        }
    }
    {
        float tr = *tres;
#pragma unroll
        for (int rt = 0; rt < 4; rt++) {
#pragma unroll
            for (int i = 0; i < 4; i++) {
                int n = n0 + rt * 16 + q * 4 + i;
                if (n < N_NODES)
                    out[(long)n * CDIM + wv * 16 + c] = acc3[rt][i] * tr;
            }
        }
    }
}

// ---------------------------------------------------------------------------
extern "C" void kernel_launch(void* const* d_in, const int* in_sizes, int n_in,
                              void* d_out, int out_size, void* d_ws, size_t ws_size,
                              hipStream_t stream) {
    const float* coords = (const float*)d_in[0];
    const float* h = (const float*)d_in[1];
    const float* flow = (const float*)d_in[2];
    const int* eidx = (const int*)d_in[3];
    const float* ln_g = (const float*)d_in[4];
    const float* ln_b = (const float*)d_in[5];
    const float* ew1 = (const float*)d_in[6];
    const float* eb1 = (const float*)d_in[7];
    const float* ew2 = (const float*)d_in[8];
    const float* eb2 = (const float*)d_in[9];
    const float* ew3 = (const float*)d_in[10];
    const float* eb3 = (const float*)d_in[11];
    const float* gw1 = (const float*)d_in[12];
    const float* gb1 = (const float*)d_in[13];
    const float* gw2 = (const float*)d_in[14];
    const float* gb2 = (const float*)d_in[15];
    const float* glw1 = (const float*)d_in[16];
    const float* glb1 = (const float*)d_in[17];
    const float* glw2 = (const float*)d_in[18];
    const float* glb2 = (const float*)d_in[19];
    const float* glw3 = (const float*)d_in[20];
    const float* glb3 = (const float*)d_in[21];
    const float* uw1 = (const float*)d_in[22];
    const float* ub1 = (const float*)d_in[23];
    const float* uw2 = (const float*)d_in[24];
    const float* ub2 = (const float*)d_in[25];
    const float* uw3 = (const float*)d_in[26];
    const float* ub3 = (const float*)d_in[27];
    const float* res = (const float*)d_in[28];

    // ---- workspace carve-up ----
    char* base = (char*)d_ws;
    unsigned short* frags = (unsigned short*)base;                 // FRAG_TOTAL us
    unsigned short* featb = (unsigned short*)(base + FRAG_TOTAL * 2); // N*64 us
    unsigned short* aggb = featb + (size_t)N_NODES * CDIM;         // N*128 us
    unsigned short* gctxb = aggb + (size_t)N_NODES * MCDIM;        // 64 us
    float* gsum = (float*)(gctxb + 64);                            // 32*64
    float* u = gsum + GSUM_REP * 64;                               // 4
    float* tres = u + 4;                                           // 1
    float* egb = tres + 1;                                         // 128
    int* rowstart = (int*)(egb + 128);                             // N+1
    int* cursor = rowstart + (N_NODES + 1);                        // N
    int* deg_int = cursor + N_NODES;                               // N
    char* tail = (char*)(deg_int + N_NODES);
    tail = (char*)(((uintptr_t)tail + 255) & ~(uintptr_t)255);
    size_t head_bytes = (size_t)(tail - base);
    size_t msg_bytes = (size_t)N_EDGES * MCDIM * 2;                // 204.8 MB bf16
    int use_msg = (ws_size >= head_bytes + msg_bytes) ? 1 : 0;
    unsigned short* msg = (unsigned short*)tail;                   // CSR slots
    float* agg = (float*)tail;                                     // fallback

    if (!use_msg)
        hipMemsetAsync(agg, 0, (size_t)N_NODES * MCDIM * sizeof(float), stream);

    prep_frags<<<FRAG_TOTAL / 256, 256, 0, stream>>>(ew1, ew2, ew3, gw1,
                                                     eb3, gb1,
                                                     uw1, uw2, uw3, frags,
                                                     deg_int, gsum, egb);
    ln_count_kernel<<<N_NODES / 4, 256, 0, stream>>>(h, ln_g, ln_b, flow, eidx,
                                                     featb, gsum, u, deg_int);
    mid_kernel<<<2, 1024, 0, stream>>>(deg_int, rowstart, cursor, gsum,
                                       glw1, glb1, glw2, glb2, glw3, glb3,
                                       res, gctxb, tres);
    edge_kernel<<<N_EDGES / 64, 256, 0, stream>>>(coords, eidx, featb, u, frags,
                                                  eb1, eb2, eb3, egb, gw2, gb2,
                                                  cursor, msg, agg, use_msg);
    gather_kernel<<<(N_NODES + 3) / 4, 256, 0, stream>>>(rowstart, msg, agg,
                                                         use_msg, aggb);
    update_kernel<<<(N_NODES + 63) / 64, 256, 0, stream>>>(featb, aggb, gctxb,
                                                           tres, frags,
                                                           ub1, ub2, ub3,
                                                           (float*)d_out);
}

// Round 10
// 454.681 us; speedup vs baseline: 1.0585x; 1.0174x over previous
//
#include <hip/hip_runtime.h>
#include <hip/hip_bf16.h>
#include <math.h>

#define N_NODES 50000
#define N_EDGES 800000
#define CDIM 64
#define MCDIM 128
#define GSUM_REP 32   // gsum replication factor (atomic decontention)

// bf16 LDS strides (elements). Row stride in dwords must be == 4 (mod 8) so
// the 16-row A-fragment ds_read_b128 pattern lands 2 lanes/bank (free, m136).
#define XS1 168       // folded edge_input, K = 132 padded -> 160 (84 dw % 8 == 4)
#define HS  136       // hidden layers, K=128                (68 dw % 8 == 4)
#define UST 264       // update_input, K=256                (132 dw % 8 == 4)

typedef __attribute__((ext_vector_type(8))) short short8;
typedef __attribute__((ext_vector_type(4))) float floatx4;
typedef __attribute__((ext_vector_type(2))) float f32x2;

// A&S 7.1.27 erf (abs err 5e-4) gelu, scalar form (used in small kernels).
__device__ __forceinline__ float gelu_fast(float x) {
    float z = fabsf(x) * 0.70710678f;
    float w = fmaf(z, fmaf(z, fmaf(z, fmaf(z, 0.078108f, 0.000972f),
                                   0.230389f), 0.278393f), 1.0f);
    float w2 = w * w;
    float r = __builtin_amdgcn_rcpf(w2 * w2);
    float m = 0.5f * fabsf(x);
    return fmaf(-m, r, fmaf(0.5f, x, m));
}

// Packed-pair gelu: identical per-element math; float2 vector arithmetic lets
// LLVM emit dual-issue v_pk_{mul,add,fma}_f32. rcp stays scalar.
__device__ __forceinline__ f32x2 gelu_pk(f32x2 x) {
    f32x2 ax = __builtin_elementwise_abs(x);
    f32x2 z = ax * 0.70710678f;
    f32x2 w = z * (z * (z * (z * 0.078108f + 0.000972f) + 0.230389f)
                   + 0.278393f) + 1.0f;
    f32x2 w2 = w * w;
    f32x2 w4 = w2 * w2;
    f32x2 r;
    r.x = __builtin_amdgcn_rcpf(w4.x);
    r.y = __builtin_amdgcn_rcpf(w4.y);
    f32x2 m = 0.5f * ax;
    return 0.5f * x + m - m * r;
}

__device__ __forceinline__ unsigned short f2bf(float f) {  // RNE fp32->bf16
    unsigned int u = __float_as_uint(f);
    unsigned int r = u + 0x7fffu + ((u >> 16) & 1u);
    return (unsigned short)(r >> 16);
}
__device__ __forceinline__ float bf2f(unsigned int lo16) {
    return __uint_as_float(lo16 << 16);
}
__device__ __forceinline__ float bf2f_hi(unsigned int u) {  // high half, no shift
    return __uint_as_float(u & 0xffff0000u);
}
// packed 2x fp32 -> bf16 pair (v_cvt_pk_bf16_f32 on gfx950)
__device__ __forceinline__ unsigned int f2bf2(float lo, float hi) {
    __hip_bfloat162 v = __float22bfloat162_rn(make_float2(lo, hi));
    union { __hip_bfloat162 b; unsigned int u; } cv;
    cv.b = v;
    return cv.u;
}
__device__ __forceinline__ ushort4 pack4(float4 v) {
    ushort4 r;
    r.x = f2bf(v.x); r.y = f2bf(v.y); r.z = f2bf(v.z); r.w = f2bf(v.w);
    return r;
}

// ---------------------------------------------------------------------------
// Weight fragment pre-swizzle. B-fragment for 16x16x32: lane l holds
// B[k = k0 + (l>>4)*8 + j][n = 16*ct + (l&15)], j=0..7 -> contiguous 16B/lane.
// ew1 is FOLDED: k<64 -> Wi+Wd ; 64..127 -> Wj-Wd ; 128..131 -> geo ; pad 160.
// FG chunk is COMPOSED: egw = ew3 @ gw1 (gate reads H2, H3 skips LDS).
// Also computes egb = eb3 @ gw1 + gb1 and zero-inits deg_int/gsum replicas.
// ---------------------------------------------------------------------------
#define F1_OFF 0               // folded ew1: 5 chunks (K=160), N=128
#define F2_OFF (5 * 4096)      // ew2: 4
#define F3_OFF (9 * 4096)      // ew3: 4
#define FG_OFF (13 * 4096)     // composed ew3@gw1: 4
#define FU1_OFF (17 * 4096)    // uw1: 8 (K=256)
#define FU2_OFF (25 * 4096)    // uw2: 4
#define FU3_OFF (29 * 4096)    // uw3: 4 chunks x 2048 (N=64)
#define FRAG_TOTAL (29 * 4096 + 4 * 2048)   // 126976 ushorts

__global__ __launch_bounds__(256) void prep_frags(
    const float* __restrict__ ew1, const float* __restrict__ ew2,
    const float* __restrict__ ew3, const float* __restrict__ gw1,
    const float* __restrict__ eb3, const float* __restrict__ gb1,
    const float* __restrict__ uw1, const float* __restrict__ uw2,
    const float* __restrict__ uw3, unsigned short* __restrict__ frags,
    int* __restrict__ deg_int, float* __restrict__ gsum,
    float* __restrict__ egb) {
    int idx = blockIdx.x * 256 + threadIdx.x;
    if (idx < N_NODES) deg_int[idx] = 0;
    if (idx < GSUM_REP * 64) gsum[idx] = 0.0f;
    if (idx < 128) {   // egb[n] = gb1[n] + eb3 . gw1[:,n]
        float s = gb1[idx];
        for (int jj = 0; jj < 128; jj++) s += eb3[jj] * gw1[jj * 128 + idx];
        egb[idx] = s;
    }
    if (idx >= FRAG_TOTAL) return;
    if (idx < F2_OFF) {  // folded ew1
        int chunk = idx >> 12;
        int rem = idx & 4095;
        int ct = rem >> 9;
        int lane = (rem >> 3) & 63;
        int j = rem & 7;
        int k = chunk * 32 + (lane >> 4) * 8 + j;
        int n = ct * 16 + (lane & 15);
        float v;
        if (k < 64)       v = ew1[k * 128 + n] + ew1[(128 + k) * 128 + n];
        else if (k < 128) v = ew1[k * 128 + n] - ew1[(64 + k) * 128 + n];
        else if (k < 132) v = ew1[(192 + k - 128) * 128 + n];
        else              v = 0.0f;
        frags[idx] = f2bf(v);
    } else if (idx >= FG_OFF && idx < FU1_OFF) {  // composed egw = ew3 @ gw1
        int chunk = idx >> 12;           // 13..16
        int rem = idx & 4095;
        int ct = rem >> 9;
        int lane = (rem >> 3) & 63;
        int j = rem & 7;
        int k = (chunk - 13) * 32 + (lane >> 4) * 8 + j;
        int n = ct * 16 + (lane & 15);
        float s = 0.0f;
        for (int jj = 0; jj < 128; jj++) s += ew3[k * 128 + jj] * gw1[jj * 128 + n];
        frags[idx] = f2bf(s);
    } else if (idx < FU3_OFF) {
        int chunk = idx >> 12;
        int rem = idx & 4095;
        int ct = rem >> 9;
        int lane = (rem >> 3) & 63;
        int j = rem & 7;
        const float* W; int kbase;
        if (chunk < 9)       { W = ew2; kbase = (chunk - 5) * 32; }
        else if (chunk < 13) { W = ew3; kbase = (chunk - 9) * 32; }
        else if (chunk < 25) { W = uw1; kbase = (chunk - 17) * 32; }
        else                 { W = uw2; kbase = (chunk - 25) * 32; }
        int k = kbase + (lane >> 4) * 8 + j;
        int n = ct * 16 + (lane & 15);
        frags[idx] = f2bf(W[k * 128 + n]);
    } else {  // uw3 [128][64]
        int rem = idx - FU3_OFF;
        int chunk = rem >> 11;
        int r = rem & 2047;
        int ct = r >> 9;
        int lane = (r >> 3) & 63;
        int j = r & 7;
        int k = chunk * 32 + (lane >> 4) * 8 + j;
        int n = ct * 16 + (lane & 15);
        frags[idx] = f2bf(uw3[k * 64 + n]);
    }
}

// ---------------------------------------------------------------------------
// MFMA helpers. acc init = column-broadcast bias.
// ---------------------------------------------------------------------------
template <int NCT>
__device__ __forceinline__ void bias_init(floatx4* acc,
                                          const float* __restrict__ bias, int lane) {
    int c = lane & 15;
#pragma unroll
    for (int ct = 0; ct < NCT; ct++) {
        float b = bias[ct * 16 + c];
        acc[ct][0] = b; acc[ct][1] = b; acc[ct][2] = b; acc[ct][3] = b;
    }
}

template <int NCH, int NCT>
__device__ __forceinline__ void mfma_layer(const unsigned short* Xl, int xs,
                                           const unsigned short* __restrict__ F,
                                           int lane, floatx4* acc) {
    int q = lane >> 4, c = lane & 15;
    const unsigned short* xrow = Xl + c * xs + q * 8;
    for (int k0 = 0; k0 < NCH; k0++) {
        short8 a = *(const short8*)(xrow + k0 * 32);
#pragma unroll
        for (int ct = 0; ct < NCT; ct++) {
            short8 b = *(const short8*)(F + ((k0 * NCT + ct) * 64 + lane) * 8);
            acc[ct] = __builtin_amdgcn_mfma_f32_16x16x32_bf16(a, b, acc[ct], 0, 0, 0);
        }
    }
}

// N-SPLIT: wave w owns col-stripe [32w, 32w+32) (ct pair {2w,2w+1}) of ALL
// 64 block rows (4 row-tiles). One b-fragment load feeds 4 MFMAs -> block
// b-fragment traffic drops 4x vs the M-split mfma_layer (R5-verified).
// Rows live tiled: row r at x1 + (r>>4)*tilestride + (r&15)*rstride.
template <int NCH>
__device__ __forceinline__ void mfma_nsplit(const unsigned short* x1,
                                            int tilestride, int rstride,
                                            const unsigned short* __restrict__ F,
                                            int lane, int w2,
                                            floatx4 acc[4][2]) {
    int q = lane >> 4, c = lane & 15;
    for (int k0 = 0; k0 < NCH; k0++) {
        short8 b0 = *(const short8*)(F + (((k0 * 8 + w2) * 64) + lane) * 8);
        short8 b1 = *(const short8*)(F + (((k0 * 8 + w2 + 1) * 64) + lane) * 8);
#pragma unroll
        for (int rt = 0; rt < 4; rt++) {
            short8 a = *(const short8*)(x1 + rt * tilestride + c * rstride
                                        + q * 8 + k0 * 32);
            acc[rt][0] = __builtin_amdgcn_mfma_f32_16x16x32_bf16(a, b0, acc[rt][0], 0, 0, 0);
            acc[rt][1] = __builtin_amdgcn_mfma_f32_16x16x32_bf16(a, b1, acc[rt][1], 0, 0, 0);
        }
    }
}

__device__ __forceinline__ void bias_init2(floatx4 acc[4][2],
                                           const float* __restrict__ bias,
                                           int lane, int w) {
    int c = lane & 15;
    float b0 = bias[w * 32 + c], b1 = bias[w * 32 + 16 + c];
#pragma unroll
    for (int rt = 0; rt < 4; rt++) {
        acc[rt][0][0] = b0; acc[rt][0][1] = b0; acc[rt][0][2] = b0; acc[rt][0][3] = b0;
        acc[rt][1][0] = b1; acc[rt][1][1] = b1; acc[rt][1][2] = b1; acc[rt][1][3] = b1;
    }
}

// gelu + packed-bf16 store of a wave's col-stripe into the tiled @HS layout.
__device__ __forceinline__ void epi2_store(floatx4 acc[4][2],
                                           unsigned short* x1, int tilestride,
                                           int lane, int w) {
    int q = lane >> 4, c = lane & 15;
#pragma unroll
    for (int rt = 0; rt < 4; rt++) {
        unsigned short* base = x1 + rt * tilestride + (q * 4) * HS + w * 32 + c;
#pragma unroll
        for (int ctl = 0; ctl < 2; ctl++) {
            f32x2 v01 = {acc[rt][ctl][0], acc[rt][ctl][1]};
            f32x2 v23 = {acc[rt][ctl][2], acc[rt][ctl][3]};
            v01 = gelu_pk(v01); v23 = gelu_pk(v23);
            unsigned int p01 = f2bf2(v01.x, v01.y), p23 = f2bf2(v23.x, v23.y);
            unsigned short* p = base + ctl * 16;
            p[0]      = (unsigned short)p01;
            p[HS]     = (unsigned short)(p01 >> 16);
            p[2 * HS] = (unsigned short)p23;
            p[3 * HS] = (unsigned short)(p23 >> 16);
        }
    }
}

// (opt) packed gelu + packed-bf16 store into an A-layout LDS tile (M-split).
// C layout: value (ct,i) at row (lane>>4)*4+i, col 16*ct+(lane&15).
template <bool GELU, int NCT>
__device__ __forceinline__ void epilogue_store(floatx4* acc,
                                               unsigned short* dst, int xs, int lane) {
    int q = lane >> 4, c = lane & 15;
    unsigned short* base = dst + (q * 4) * xs + c;
#pragma unroll
    for (int ct = 0; ct < NCT; ct++) {
        f32x2 v01 = {acc[ct][0], acc[ct][1]};
        f32x2 v23 = {acc[ct][2], acc[ct][3]};
        if (GELU) { v01 = gelu_pk(v01); v23 = gelu_pk(v23); }
        unsigned int p01 = f2bf2(v01.x, v01.y), p23 = f2bf2(v23.x, v23.y);
        unsigned short* p = base + ct * 16;
        p[0]      = (unsigned short)p01;
        p[xs]     = (unsigned short)(p01 >> 16);
        p[2 * xs] = (unsigned short)p23;
        p[3 * xs] = (unsigned short)(p23 >> 16);
    }
}

// ---------------------------------------------------------------------------
// LayerNorm (bf16 out) + global-mean partials (replicated atomics)
// + flow_dir normalize + degree
// ---------------------------------------------------------------------------
__global__ __launch_bounds__(256) void ln_count_kernel(
    const float* __restrict__ h, const float* __restrict__ ln_g,
    const float* __restrict__ ln_b, const float* __restrict__ flow_dir,
    const int* __restrict__ eidx, unsigned short* __restrict__ featb,
    float* __restrict__ gsum, float* __restrict__ u_out,
    int* __restrict__ deg_int) {
    int t = threadIdx.x;
    int ln = t >> 6;
    int c = t & 63;
    int n = blockIdx.x * 4 + ln;

    float x = h[n * CDIM + c];
    float s = x;
#pragma unroll
    for (int off = 32; off > 0; off >>= 1) s += __shfl_xor(s, off, 64);
    float mu = s * (1.0f / 64.0f);
    float d = x - mu;
    float v = d * d;
#pragma unroll
    for (int off = 32; off > 0; off >>= 1) v += __shfl_xor(v, off, 64);
    float rs = 1.0f / sqrtf(v * (1.0f / 64.0f) + 1e-5f);
    float f = d * rs * ln_g[c] + ln_b[c];
    featb[n * CDIM + c] = f2bf(f);

    __shared__ float fs[4][64];
    fs[ln][c] = f;
    __syncthreads();   // cross-wave reduction below (real dependency, keep)
    if (t < 64) {
        float p = fs[0][t] + fs[1][t] + fs[2][t] + fs[3][t];
        atomicAdd(&gsum[(blockIdx.x & (GSUM_REP - 1)) * 64 + t], p);
        int e = blockIdx.x * 64 + t;           // 12500*64 == N_EDGES
        atomicAdd(&deg_int[eidx[e]], 1);
    }
    if (blockIdx.x == 0 && t == 0) {
        float ux = flow_dir[0], uy = flow_dir[1], uz = flow_dir[2];
        float nrm = sqrtf(ux * ux + uy * uy + uz * uz) + 1e-8f;
        u_out[0] = ux / nrm;
        u_out[1] = uy / nrm;
        u_out[2] = uz / nrm;
    }
}

// ---------------------------------------------------------------------------
// Merged mid kernel: block 0 = exclusive prefix scan; block 1 = global MLP
// (first reducing the gsum replicas).
// ---------------------------------------------------------------------------
__global__ __launch_bounds__(1024) void mid_kernel(
    const int* __restrict__ deg_int, int* __restrict__ rowstart,
    int* __restrict__ cursor,
    const float* __restrict__ gsum,
    const float* __restrict__ glw1, const float* __restrict__ glb1,
    const float* __restrict__ glw2, const float* __restrict__ glb2,
    const float* __restrict__ glw3, const float* __restrict__ glb3,
    const float* __restrict__ res_scale,
    unsigned short* __restrict__ gctxb, float* __restrict__ tres) {
    int t = threadIdx.x;
    if (blockIdx.x == 0) {
        __shared__ int wsum[16];
        __shared__ int run;
        int wid = t >> 6, lane = t & 63;
        int4 vs[13];
#pragma unroll
        for (int chunk = 0; chunk < 13; chunk++) {
            int base = chunk * 4096 + t * 4;
            int4 v = {0, 0, 0, 0};
            if (base + 3 < N_NODES) {
                v = *(const int4*)(deg_int + base);
            } else {
                if (base < N_NODES) v.x = deg_int[base];
                if (base + 1 < N_NODES) v.y = deg_int[base + 1];
                if (base + 2 < N_NODES) v.z = deg_int[base + 2];
                if (base + 3 < N_NODES) v.w = deg_int[base + 3];
            }
            vs[chunk] = v;
        }
        if (t == 0) run = 0;
        __syncthreads();
#pragma unroll
        for (int chunk = 0; chunk < 13; chunk++) {
            int base = chunk * 4096 + t * 4;
            int4 v = vs[chunk];
            int s1 = v.x, s2 = s1 + v.y, s3 = s2 + v.z, s4 = s3 + v.w;
            int x = s4;
#pragma unroll
            for (int off = 1; off < 64; off <<= 1) {
                int y = __shfl_up(x, off, 64);
                if (lane >= off) x += y;
            }
            if (lane == 63) wsum[wid] = x;
            __syncthreads();
            if (t < 16) {
                int sv = wsum[t];
#pragma unroll
                for (int off = 1; off < 16; off <<= 1) {
                    int y = __shfl_up(sv, off, 16);
                    if (t >= off) sv += y;
                }
                wsum[t] = sv;
            }
            __syncthreads();
            int run_l = run;
            int wpre = (wid == 0) ? 0 : wsum[wid - 1];
            int toff = run_l + wpre + (x - s4);
            int e0 = toff, e1 = toff + s1, e2 = toff + s2, e3 = toff + s3;
            if (base <= N_NODES) rowstart[base] = e0;
            if (base + 1 <= N_NODES) rowstart[base + 1] = e1;
            if (base + 2 <= N_NODES) rowstart[base + 2] = e2;
            if (base + 3 <= N_NODES) rowstart[base + 3] = e3;
            if (base < N_NODES) cursor[base] = e0;
            if (base + 1 < N_NODES) cursor[base + 1] = e1;
            if (base + 2 < N_NODES) cursor[base + 2] = e2;
            if (base + 3 < N_NODES) cursor[base + 3] = e3;
            __syncthreads();
            if (t == 0) run = run_l + wsum[15];
            __syncthreads();
        }
    } else {
        __shared__ float a[64], b[64];
        float s = 0.0f;
        if (t < 64) {
            float acc = 0.0f;
            for (int r = 0; r < GSUM_REP; r++) acc += gsum[r * 64 + t];
            a[t] = acc * (1.0f / (float)N_NODES);
        }
        __syncthreads();
        if (t < 64) {
            s = glb1[t];
            for (int k = 0; k < 64; k++) s += a[k] * glw1[k * 64 + t];
            b[t] = gelu_fast(s);
        }
        __syncthreads();
        if (t < 64) {
            s = glb2[t];
            for (int k = 0; k < 64; k++) s += b[k] * glw2[k * 64 + t];
        }
        __syncthreads();
        if (t < 64) a[t] = gelu_fast(s);
        __syncthreads();
        if (t < 64) {
            s = glb3[t];
            for (int k = 0; k < 64; k++) s += a[k] * glw3[k * 64 + t];
            gctxb[t] = f2bf(s);
        }
        if (t == 0) *tres = tanhf(res_scale[0]);
    }
}

// ---------------------------------------------------------------------------
// Fused MFMA edge pipeline, N-SPLIT (R6-verified config): 64 edges/block,
// 4 waves; each wave owns a 32-col stripe of ALL 64 edges -> every B-fragment
// load feeds 4 MFMAs (R5: 300->250) + deferred cursor atomic + 6 blocks/CU
// (R6: 250->237, FETCH 85.9MB). R7 proved 7 blocks overflows L2 -> 6 optimal.
// ---------------------------------------------------------------------------
struct SmemE {
    unsigned short x1[64 * XS1];   // 21504 B, all pipeline stages live here
    float gatep[4][64];            // per-wave gate partials
    int pos[64];
    int rows[64];
};

__global__ __launch_bounds__(256, 6) void edge_kernel(
    const float* __restrict__ coords, const int* __restrict__ eidx,
    const unsigned short* __restrict__ featb, const float* __restrict__ u,
    const unsigned short* __restrict__ frags,
    const float* __restrict__ eb1, const float* __restrict__ eb2,
    const float* __restrict__ eb3,
    const float* __restrict__ egb, const float* __restrict__ gw2,
    const float* __restrict__ gb2,
    int* __restrict__ cursor, unsigned short* __restrict__ msg,
    float* __restrict__ agg, int use_msg) {
    __shared__ SmemE sm;
    int t = threadIdx.x;
    int wv = t >> 6;
    int lane = t & 63;
    int e0 = blockIdx.x * 64;
    int q = lane >> 4, c = lane & 15;
    int w2 = wv * 2;                      // this wave's ct stripe {w2, w2+1}

    int rowreg;                            // staged edge's row (sub==0 teams)
    {   // stage folded edge_input (bf16 copies, no cvt): 4 threads/edge
        int le = t >> 2, sub = t & 3;
        int e = e0 + le;
        int row = eidx[e];
        int col = eidx[N_EDGES + e];
        rowreg = row;
        const uint4* fi4 = (const uint4*)(featb + (long)row * CDIM);
        const uint4* fj4 = (const uint4*)(featb + (long)col * CDIM);
        unsigned short* xr = sm.x1 + le * XS1;
        *(uint4*)(xr + sub * 16) = fi4[sub * 2];
        *(uint4*)(xr + sub * 16 + 8) = fi4[sub * 2 + 1];
        *(uint4*)(xr + 64 + sub * 16) = fj4[sub * 2];
        *(uint4*)(xr + 64 + sub * 16 + 8) = fj4[sub * 2 + 1];
        ushort4 z = {0, 0, 0, 0};
        if (sub == 0) {
            sm.rows[le] = row;
            float xix = coords[row * 3], xiy = coords[row * 3 + 1], xiz = coords[row * 3 + 2];
            float xjx = coords[col * 3], xjy = coords[col * 3 + 1], xjz = coords[col * 3 + 2];
            float rx = xix - xjx, ry = xiy - xjy, rz = xiz - xjz;
            float ux = u[0], uy = u[1], uz = u[2];
            float4 sc;
            sc.x = rx * rx + ry * ry + rz * rz;
            sc.y = xix * ux + xiy * uy + xiz * uz;
            sc.z = xjx * ux + xjy * uy + xjz * uz;
            sc.w = rx * ux + ry * uy + rz * uz;
            *(ushort4*)(xr + 128) = pack4(sc);
        } else if (sub == 1) {
            *(ushort4*)(xr + 132) = z; *(ushort4*)(xr + 136) = z; *(ushort4*)(xr + 140) = z;
        } else if (sub == 2) {
            *(ushort4*)(xr + 144) = z; *(ushort4*)(xr + 148) = z;
        } else {
            *(ushort4*)(xr + 152) = z; *(ushort4*)(xr + 156) = z;
        }
    }
    __syncthreads();

    floatx4 acc[4][2];

    // L1 (folded, K=160): read all rows @XS1 (stripe cols) | B | write @HS
    bias_init2(acc, eb1, lane, wv);
    mfma_nsplit<5>(sm.x1, 16 * XS1, XS1, frags + F1_OFF, lane, w2, acc);
    __syncthreads();                       // all XS1 reads done before HS writes
    epi2_store(acc, sm.x1, 16 * XS1, lane, wv);
    __syncthreads();

    // L2: H1 -> H2 (in-place row-for-row @HS): read | B | write
    bias_init2(acc, eb2, lane, wv);
    mfma_nsplit<4>(sm.x1, 16 * XS1, HS, frags + F2_OFF, lane, w2, acc);
    __syncthreads();
    epi2_store(acc, sm.x1, 16 * XS1, lane, wv);
    __syncthreads();

    // Deferred CSR slot acquisition: issue the contended atomic NOW so its
    // latency hides under the gate+L3+store compute below. Result parked in
    // a VGPR; LDS publish happens right before the final barrier.
    int posreg = 0;
    if (use_msg && (t & 3) == 0) posreg = atomicAdd(&cursor[rowreg], 1);

    // Gate G1 stripe (composed ew3@gw1) -> per-edge partials -> gatep
    bias_init2(acc, egb, lane, wv);
    mfma_nsplit<4>(sm.x1, 16 * XS1, HS, frags + FG_OFF, lane, w2, acc);
    {
#pragma unroll
        for (int rt = 0; rt < 4; rt++) {
            float w2v0 = gw2[wv * 32 + c];
            float w2v1 = gw2[wv * 32 + 16 + c];
            f32x2 g01a = gelu_pk((f32x2){acc[rt][0][0], acc[rt][0][1]});
            f32x2 g23a = gelu_pk((f32x2){acc[rt][0][2], acc[rt][0][3]});
            f32x2 g01b = gelu_pk((f32x2){acc[rt][1][0], acc[rt][1][1]});
            f32x2 g23b = gelu_pk((f32x2){acc[rt][1][2], acc[rt][1][3]});
            float p[4];
            p[0] = g01a.x * w2v0 + g01b.x * w2v1;
            p[1] = g01a.y * w2v0 + g01b.y * w2v1;
            p[2] = g23a.x * w2v0 + g23b.x * w2v1;
            p[3] = g23a.y * w2v0 + g23b.y * w2v1;
#pragma unroll
            for (int i = 0; i < 4; i++) {
#pragma unroll
                for (int mask = 1; mask < 16; mask <<= 1)
                    p[i] += __shfl_xor(p[i], mask, 64);
            }
            if (c == 0) {
#pragma unroll
                for (int i = 0; i < 4; i++)
                    sm.gatep[wv][rt * 16 + q * 4 + i] = p[i];
            }
        }
    }

    // L3: H2 -> h3 stripe (fp32 regs; reads H2 like the gate did)
    floatx4 acch[4][2];
    bias_init2(acch, eb3, lane, wv);
    mfma_nsplit<4>(sm.x1, 16 * XS1, HS, frags + F3_OFF, lane, w2, acch);
    __syncthreads();   // gatep visible + all H2 reads done before store clobbers

    // finalize gates (redundant per-lane, broadcast LDS reads within 16-group)
    float gb = gb2[0];
    float g4[4][4];
#pragma unroll
    for (int rt = 0; rt < 4; rt++) {
#pragma unroll
        for (int i = 0; i < 4; i++) {
            int e = rt * 16 + q * 4 + i;
            float z = sm.gatep[0][e] + sm.gatep[1][e] + sm.gatep[2][e]
                    + sm.gatep[3][e] + gb;
            g4[rt][i] = 1.0f / (1.0f + __expf(-z));
        }
    }

    if (use_msg) {
        {   // scaled bf16 message stripe into tiled @HS layout from h3 regs
#pragma unroll
            for (int rt = 0; rt < 4; rt++) {
                unsigned short* base = sm.x1 + rt * (16 * XS1) + (q * 4) * HS
                                     + wv * 32 + c;
#pragma unroll
                for (int ctl = 0; ctl < 2; ctl++) {
                    unsigned int p01 = f2bf2(acch[rt][ctl][0] * g4[rt][0],
                                             acch[rt][ctl][1] * g4[rt][1]);
                    unsigned int p23 = f2bf2(acch[rt][ctl][2] * g4[rt][2],
                                             acch[rt][ctl][3] * g4[rt][3]);
                    unsigned short* p = base + ctl * 16;
                    p[0]      = (unsigned short)p01;
                    p[HS]     = (unsigned short)(p01 >> 16);
                    p[2 * HS] = (unsigned short)p23;
                    p[3 * HS] = (unsigned short)(p23 >> 16);
                }
            }
        }
        // publish the deferred CSR slots (atomic latency long since covered)
        if ((t & 3) == 0) sm.pos[t >> 2] = posreg;
        __syncthreads();
        {   // coalesced 256B-row stream to msg[pos[e]] (unchanged from R0)
            int le = t >> 2, sub = t & 3;
            long base = (long)sm.pos[le] * MCDIM;
            const unsigned short* src = sm.x1 + (le >> 4) * 16 * XS1 + (le & 15) * HS;
#pragma unroll
            for (int m = 0; m < 4; m++) {
                int off = m * 32 + sub * 8;
                *(short8*)(msg + base + off) = *(const short8*)(src + off);
            }
        }
    } else {
#pragma unroll
        for (int rt = 0; rt < 4; rt++) {
#pragma unroll
            for (int i = 0; i < 4; i++) {
                int row = sm.rows[rt * 16 + q * 4 + i];
                float* agr = agg + (long)row * MCDIM + wv * 32 + c;
#pragma unroll
                for (int ctl = 0; ctl < 2; ctl++)
                    atomicAdd(agr + ctl * 16, g4[rt][i] * acch[rt][ctl][i]);
            }
        }
    }
}

// ---------------------------------------------------------------------------
// Gather, QUAD-ROW version (R9 rerun — R9's bench was an infra failure, not
// a kernel verdict): one wave per node; each lane reads uint4 (16B) so one
// wave-iteration covers FOUR msg rows (1KB in flight vs 512B). Halves loop
// iterations and doubles outstanding bytes for the latency-suspect
// dependent-accumulate loop. Reduction across the 4 row groups via 2
// shfl_xor; lanes 0-15 pack+write the node's 256B aggb row.
// ---------------------------------------------------------------------------
__global__ __launch_bounds__(256) void gather_kernel(
    const int* __restrict__ rowstart, const unsigned short* __restrict__ msg,
    const float* __restrict__ agg, int use_msg,
    unsigned short* __restrict__ aggb) {
    int wv = threadIdx.x >> 6, lane = threadIdx.x & 63;
    int n = blockIdx.x * 4 + wv;
    if (n >= N_NODES) return;
    int rs = rowstart[n], re = rowstart[n + 1];
    int deg = re - rs;
    if (use_msg) {
        const unsigned short* base = msg + (long)rs * MCDIM;
        int r = lane >> 4;              // row within quad
        int cs = (lane & 15) * 8;       // 8-channel slice
        float s0 = 0, s1 = 0, s2 = 0, s3 = 0, s4 = 0, s5 = 0, s6 = 0, s7 = 0;
        int quads = deg >> 2;
        for (int i = 0; i < quads; i++) {
            uint4 v = *(const uint4*)(base + ((long)(i * 4 + r)) * MCDIM + cs);
            s0 += bf2f(v.x & 0xffffu); s1 += bf2f_hi(v.x);
            s2 += bf2f(v.y & 0xffffu); s3 += bf2f_hi(v.y);
            s4 += bf2f(v.z & 0xffffu); s5 += bf2f_hi(v.z);
            s6 += bf2f(v.w & 0xffffu); s7 += bf2f_hi(v.w);
        }
        int tail = deg & 3;
        if (r < tail) {
            uint4 v = *(const uint4*)(base + ((long)(quads * 4 + r)) * MCDIM + cs);
            s0 += bf2f(v.x & 0xffffu); s1 += bf2f_hi(v.x);
            s2 += bf2f(v.y & 0xffffu); s3 += bf2f_hi(v.y);
            s4 += bf2f(v.z & 0xffffu); s5 += bf2f_hi(v.z);
            s6 += bf2f(v.w & 0xffffu); s7 += bf2f_hi(v.w);
        }
        // reduce across the 4 row-groups (lane&15 preserved by xor 16/32)
#pragma unroll
        for (int m = 16; m < 64; m <<= 1) {
            s0 += __shfl_xor(s0, m, 64); s1 += __shfl_xor(s1, m, 64);
            s2 += __shfl_xor(s2, m, 64); s3 += __shfl_xor(s3, m, 64);
            s4 += __shfl_xor(s4, m, 64); s5 += __shfl_xor(s5, m, 64);
            s6 += __shfl_xor(s6, m, 64); s7 += __shfl_xor(s7, m, 64);
        }
        if (lane < 16) {
            float inv = 1.0f / fmaxf((float)deg, 1.0f);
            uint4 o;
            o.x = f2bf2(s0 * inv, s1 * inv);
            o.y = f2bf2(s2 * inv, s3 * inv);
            o.z = f2bf2(s4 * inv, s5 * inv);
            o.w = f2bf2(s6 * inv, s7 * inv);
            *(uint4*)(aggb + (long)n * MCDIM + lane * 8) = o;
        }
    } else {
        float a0 = 0.0f, a1 = 0.0f, a2 = 0.0f, a3 = 0.0f;
        if (lane < 32) {
            const float4 v = *(const float4*)(agg + (long)n * MCDIM + lane * 4);
            a0 = v.x; a1 = v.y; a2 = v.z; a3 = v.w;
            float inv = 1.0f / fmaxf((float)deg, 1.0f);
            uint2 o;
            o.x = f2bf2(a0 * inv, a1 * inv);
            o.y = f2bf2(a2 * inv, a3 * inv);
            *(uint2*)(aggb + (long)n * MCDIM + lane * 4) = o;
        }
    }
}

// ---------------------------------------------------------------------------
// MFMA node update: single-buffer slices, M-split (R6-verified; R8's n-split
// was neutral-to-negative — update is not b-stream-bound at 3 blocks/CU).
// 64 nodes/block, 4 blocks/CU.
// ---------------------------------------------------------------------------
struct SmemU {
    unsigned short ui[64 * UST];   // 33792 B, all stages live here
};

__global__ __launch_bounds__(256, 4) void update_kernel(
    const unsigned short* __restrict__ featb, const unsigned short* __restrict__ aggb,
    const unsigned short* __restrict__ gctxb, const float* __restrict__ tres,
    const unsigned short* __restrict__ frags,
    const float* __restrict__ ub1, const float* __restrict__ ub2,
    const float* __restrict__ ub3,
    float* __restrict__ out) {
    __shared__ SmemU sm;
    int t = threadIdx.x;
    int wv = t >> 6;
    int lane = t & 63;
    int n0 = blockIdx.x * 64;
    unsigned short* slice = sm.ui + wv * 16 * UST;   // wave-private

    {   // stage [feat | agg | gctx] (all bf16 copies): 4 threads/node
        int ln = t >> 2, sub = t & 3;
        int n = n0 + ln;
        unsigned short* ur = sm.ui + ln * UST;
        if (n < N_NODES) {
            const uint4* f4 = (const uint4*)(featb + (long)n * CDIM);
            *(uint4*)(ur + sub * 16) = f4[sub * 2];
            *(uint4*)(ur + sub * 16 + 8) = f4[sub * 2 + 1];
            const uint4* a4 = (const uint4*)(aggb + (long)n * MCDIM);
            *(uint4*)(ur + 64 + sub * 32) = a4[sub * 4];
            *(uint4*)(ur + 64 + sub * 32 + 8) = a4[sub * 4 + 1];
            *(uint4*)(ur + 64 + sub * 32 + 16) = a4[sub * 4 + 2];
            *(uint4*)(ur + 64 + sub * 32 + 24) = a4[sub * 4 + 3];
            const uint4* g4 = (const uint4*)gctxb;
            *(uint4*)(ur + 192 + sub * 16) = g4[sub * 2];
            *(uint4*)(ur + 192 + sub * 16 + 8) = g4[sub * 2 + 1];
        } else {
            uint4 z = {0, 0, 0, 0};
#pragma unroll
            for (int m = 0; m < 8; m++) *(uint4*)(ur + sub * 64 + m * 8) = z;
        }
    }
    __syncthreads();

    floatx4 acc[8];
    bias_init<8>(acc, ub1, lane);
    mfma_layer<8, 8>(slice, UST, frags + FU1_OFF, lane, acc);
    epilogue_store<true, 8>(acc, slice, HS, lane);
    __syncthreads();

    bias_init<8>(acc, ub2, lane);
    mfma_layer<4, 8>(slice, HS, frags + FU2_OFF, lane, acc);
    epilogue_store<true, 8>(acc, slice, HS, lane);
    __syncthreads();

    floatx4 acc3[4];
    bias_init<4>(acc3, ub3, lane);
    mfma_layer<4, 4>(slice, HS, frags + FU3_OFF, lane, acc3);
    {
        int q = lane >> 4, c = lane & 15;
        float tr = *tres;
#pragma unroll
        for (int ct = 0; ct < 4; ct++) {
#pragma unroll
            for (int i = 0; i < 4; i++) {
                int n = n0 + wv * 16 + q * 4 + i;
                if (n < N_NODES) out[(long)n * CDIM + ct * 16 + c] = acc3[ct][i] * tr;
            }
        }
    }
}

// ---------------------------------------------------------------------------
extern "C" void kernel_launch(void* const* d_in, const int* in_sizes, int n_in,
                              void* d_out, int out_size, void* d_ws, size_t ws_size,
                              hipStream_t stream) {
    const float* coords = (const float*)d_in[0];
    const float* h = (const float*)d_in[1];
    const float* flow = (const float*)d_in[2];
    const int* eidx = (const int*)d_in[3];
    const float* ln_g = (const float*)d_in[4];
    const float* ln_b = (const float*)d_in[5];
    const float* ew1 = (const float*)d_in[6];
    const float* eb1 = (const float*)d_in[7];
    const float* ew2 = (const float*)d_in[8];
    const float* eb2 = (const float*)d_in[9];
    const float* ew3 = (const float*)d_in[10];
    const float* eb3 = (const float*)d_in[11];
    const float* gw1 = (const float*)d_in[12];
    const float* gb1 = (const float*)d_in[13];
    const float* gw2 = (const float*)d_in[14];
    const float* gb2 = (const float*)d_in[15];
    const float* glw1 = (const float*)d_in[16];
    const float* glb1 = (const float*)d_in[17];
    const float* glw2 = (const float*)d_in[18];
    const float* glb2 = (const float*)d_in[19];
    const float* glw3 = (const float*)d_in[20];
    const float* glb3 = (const float*)d_in[21];
    const float* uw1 = (const float*)d_in[22];
    const float* ub1 = (const float*)d_in[23];
    const float* uw2 = (const float*)d_in[24];
    const float* ub2 = (const float*)d_in[25];
    const float* uw3 = (const float*)d_in[26];
    const float* ub3 = (const float*)d_in[27];
    const float* res = (const float*)d_in[28];

    // ---- workspace carve-up ----
    char* base = (char*)d_ws;
    unsigned short* frags = (unsigned short*)base;                 // FRAG_TOTAL us
    unsigned short* featb = (unsigned short*)(base + FRAG_TOTAL * 2); // N*64 us
    unsigned short* aggb = featb + (size_t)N_NODES * CDIM;         // N*128 us
    unsigned short* gctxb = aggb + (size_t)N_NODES * MCDIM;        // 64 us
    float* gsum = (float*)(gctxb + 64);                            // 32*64
    float* u = gsum + GSUM_REP * 64;                               // 4
    float* tres = u + 4;                                           // 1
    float* egb = tres + 1;                                         // 128
    int* rowstart = (int*)(egb + 128);                             // N+1
    int* cursor = rowstart + (N_NODES + 1);                        // N
    int* deg_int = cursor + N_NODES;                               // N
    char* tail = (char*)(deg_int + N_NODES);
    tail = (char*)(((uintptr_t)tail + 255) & ~(uintptr_t)255);
    size_t head_bytes = (size_t)(tail - base);
    size_t msg_bytes = (size_t)N_EDGES * MCDIM * 2;                // 204.8 MB bf16
    int use_msg = (ws_size >= head_bytes + msg_bytes) ? 1 : 0;
    unsigned short* msg = (unsigned short*)tail;                   // CSR slots
    float* agg = (float*)tail;                                     // fallback

    if (!use_msg)
        hipMemsetAsync(agg, 0, (size_t)N_NODES * MCDIM * sizeof(float), stream);

    prep_frags<<<FRAG_TOTAL / 256, 256, 0, stream>>>(ew1, ew2, ew3, gw1,
                                                     eb3, gb1,
                                                     uw1, uw2, uw3, frags,
                                                     deg_int, gsum, egb);
    ln_count_kernel<<<N_NODES / 4, 256, 0, stream>>>(h, ln_g, ln_b, flow, eidx,
                                                     featb, gsum, u, deg_int);
    mid_kernel<<<2, 1024, 0, stream>>>(deg_int, rowstart, cursor, gsum,
                                       glw1, glb1, glw2, glb2, glw3, glb3,
                                       res, gctxb, tres);
    edge_kernel<<<N_EDGES / 64, 256, 0, stream>>>(coords, eidx, featb, u, frags,
                                                  eb1, eb2, eb3, egb, gw2, gb2,
                                                  cursor, msg, agg, use_msg);
    gather_kernel<<<(N_NODES + 3) / 4, 256, 0, stream>>>(rowstart, msg, agg,
                                                         use_msg, aggb);
    update_kernel<<<(N_NODES + 63) / 64, 256, 0, stream>>>(featb, aggb, gctxb,
                                                           tres, frags,
                                                           ub1, ub2, ub3,
                                                           (float*)d_out);
}